// Round 3
// baseline (3335.973 us; speedup 1.0000x reference)
//
#include <hip/hip_runtime.h>
#include <hip/hip_bf16.h>

// Qwen3-MoE forward, MI355X. Router-critical math is fp32-faithful: dense GEMMs
// AND attention run on the bf16 MFMA pipe via an EXACT 3-plane bf16 split
// (x == xh+xm+xl, truncation split, 6 cross products -> rel err ~1e-7 <
// fp32 reorder noise), so top-k expert selection matches the fp32 reference.
// bf16 (single-plane) only for the final logits GEMM.
// R3: LDS-free direct-reg fragments for logits GEMM; direct-reg A + single-
// barrier double-buffered B staging for the split GEMMs (LDS round-trip was
// the measured critical path: MfmaUtil 27%, ds ops ~2.4x MFMA cycles).

constexpr int S_ = 2048, D_ = 1024, H_ = 16, HD_ = 64, E_ = 8, MF_ = 768, V_ = 32000;

typedef short  short8 __attribute__((ext_vector_type(8)));
typedef float  f32x4  __attribute__((ext_vector_type(4)));

static __device__ __forceinline__ unsigned short f2bf(float f) {
    unsigned u = __float_as_uint(f);
    u += 0x7FFF + ((u >> 16) & 1);          // RNE
    return (unsigned short)(u >> 16);
}

static __device__ __forceinline__ short8 u2s8(uint4 u) {
    union { uint4 a; short8 b; } x; x.a = u; return x.b;
}

// ---------------- embed gather ----------------
__global__ __launch_bounds__(256) void k_gather(const int* __restrict__ ids,
                                                const float* __restrict__ emb,
                                                float* __restrict__ h) {
    int tok = blockIdx.x;
    int id  = ids[tok];
    const float4* src = (const float4*)(emb + (long)id * D_);
    float4*       dst = (float4*)(h + (long)tok * D_);
    dst[threadIdx.x] = src[threadIdx.x];
}

// ---------------- rmsnorm (row per block) ----------------
template <int BF>
__global__ __launch_bounds__(256) void k_rmsnorm(const float* __restrict__ in,
                                                 const float* __restrict__ w,
                                                 float* __restrict__ outf,
                                                 unsigned short* __restrict__ outb) {
    int row = blockIdx.x, t = threadIdx.x;
    float4 x = ((const float4*)(in + (long)row * D_))[t];
    float ss = x.x * x.x + x.y * x.y + x.z * x.z + x.w * x.w;
#pragma unroll
    for (int m = 32; m >= 1; m >>= 1) ss += __shfl_xor(ss, m);
    __shared__ float ps[4];
    if ((t & 63) == 0) ps[t >> 6] = ss;
    __syncthreads();
    float tot   = ps[0] + ps[1] + ps[2] + ps[3];
    float scale = 1.0f / sqrtf(tot * (1.0f / D_) + 1e-6f);
    float4 wv = ((const float4*)w)[t];
    float4 o;
    o.x = x.x * scale * wv.x; o.y = x.y * scale * wv.y;
    o.z = x.z * scale * wv.z; o.w = x.w * scale * wv.w;
    if (BF) {
        ushort4 ub;
        ub.x = f2bf(o.x); ub.y = f2bf(o.y); ub.z = f2bf(o.z); ub.w = f2bf(o.w);
        *(ushort4*)(outb + (long)row * D_ + t * 4) = ub;
    } else {
        ((float4*)(outf + (long)row * D_))[t] = o;
    }
}

// ---------------- per-head RMSNorm + RoPE (one wave per (tensor,tok,head)) ----
__global__ __launch_bounds__(256) void k_qkrope(float* __restrict__ q, float* __restrict__ k,
                                                const float* __restrict__ qn,
                                                const float* __restrict__ kn,
                                                const float* __restrict__ cosb,
                                                const float* __restrict__ sinb) {
    int wid  = (blockIdx.x << 2) | (threadIdx.x >> 6);   // 0 .. 65535
    int lane = threadIdx.x & 63;
    int tensor = wid >> 15;
    int rem    = wid & 32767;
    int tok = rem >> 4, head = rem & 15;
    float* ptr = tensor ? k : q;
    const float* nw = tensor ? kn : qn;
    long off = ((long)tok * H_ + head) * HD_ + lane;
    float v = ptr[off];
    float ss = v * v;
#pragma unroll
    for (int m = 32; m >= 1; m >>= 1) ss += __shfl_xor(ss, m);
    float xn = v * (1.0f / sqrtf(ss * (1.0f / HD_) + 1e-6f)) * nw[lane];
    float other = __shfl_xor(xn, 32);
    float rot = (lane < 32) ? -other : other;
    ptr[off] = xn * cosb[tok * HD_ + lane] + rot * sinb[tok * HD_ + lane];
}

// ---------------- exact 3-plane bf16 split helpers ----------------
static __device__ __forceinline__ void splitpack2(float x0, float x1,
                                                  unsigned& wh, unsigned& wm,
                                                  unsigned& wl) {
    unsigned u0 = __float_as_uint(x0), u1 = __float_as_uint(x1);
    unsigned h0 = u0 & 0xFFFF0000u,    h1 = u1 & 0xFFFF0000u;
    float r0 = x0 - __uint_as_float(h0), r1 = x1 - __uint_as_float(h1);
    unsigned m0 = __float_as_uint(r0) & 0xFFFF0000u;
    unsigned m1 = __float_as_uint(r1) & 0xFFFF0000u;
    float s0 = r0 - __uint_as_float(m0), s1 = r1 - __uint_as_float(m1);
    unsigned l0 = __float_as_uint(s0),   l1 = __float_as_uint(s1);
    wh = (h0 >> 16) | h1;
    wm = (m0 >> 16) | m1;
    wl = (l0 >> 16) | (l1 & 0xFFFF0000u);
}

static __device__ __forceinline__ void split8(const float* v,
                                              uint4& qh, uint4& qm, uint4& ql) {
    unsigned ph[4], pm[4], pl[4];
#pragma unroll
    for (int j = 0; j < 4; j++) splitpack2(v[2 * j], v[2 * j + 1], ph[j], pm[j], pl[j]);
    qh = make_uint4(ph[0], ph[1], ph[2], ph[3]);
    qm = make_uint4(pm[0], pm[1], pm[2], pm[3]);
    ql = make_uint4(pl[0], pl[1], pl[2], pl[3]);
}

// ---------------- split-bf16 MFMA GEMM: C[M,N] = A[M,K] @ B[K,N] ----------------
// A read per-lane direct from global (K-contig) and split in registers.
// B (fp32 [k][n]) staged transposed into double-buffered LDS bf16 planes,
// ONE barrier per 32-K step (loads before MFMA, writes after).
template <int IND, int EPI>
__global__ __launch_bounds__(256) void k_gemm_s6(const float* __restrict__ A,
                                                 const float* __restrict__ B0,
                                                 const float* __restrict__ B1,
                                                 const float* __restrict__ B2,
                                                 float* __restrict__ C,
                                                 const int* __restrict__ offs,
                                                 const int* __restrict__ rows,
                                                 const float* __restrict__ rwgt,
                                                 float* __restrict__ hout,
                                                 int Mtot, int N, int K,
                                                 long bStrideZ, long cStrideZ) {
    int z = blockIdx.z;
    int ms, me;
    if (offs) { ms = offs[z]; me = offs[z + 1]; }
    else      { ms = 0; me = Mtot; }
    int p0 = ms + blockIdx.y * 128;
    if (p0 >= me) return;
    const float* Bz;
    if (B1) Bz = (z == 0) ? B0 : (z == 1) ? B1 : B2;
    else    Bz = B0 + (long)z * bStrideZ;
    float* Cz = C ? (C + (long)z * cStrideZ) : nullptr;
    int n0 = blockIdx.x * 128;

    __shared__ __align__(16) unsigned short Bs[2][3][128][40];  // dbuf x planes h/m/l, [n][k]

    int t = threadIdx.x;
    int lane = t & 63, wave = t >> 6;
    int wm = (wave >> 1) * 64, wn = (wave & 1) * 64;
    int ln = lane & 15, lq = lane >> 4;

    f32x4 acc[4][4];
    f32x4 zero4 = {0.f, 0.f, 0.f, 0.f};
#pragma unroll
    for (int r = 0; r < 4; r++)
#pragma unroll
        for (int c = 0; c < 4; c++) acc[r][c] = zero4;

    // A: per-lane direct fragment pointers (row = p0+wm+16r+ln, k-off = lq*8)
    const float* aptr[4];
#pragma unroll
    for (int r = 0; r < 4; r++) {
        int p = p0 + wm + 16 * r + ln;
        aptr[r] = nullptr;
        if (p < me) {
            int srow = IND ? rows[p] : p;
            aptr[r] = A + (long)srow * K + lq * 8;
        }
    }
    // B staging: thread owns one n (t>>1) and one k-half; 16 strided dwords.
    int brow = t >> 1, bk0 = (t & 1) * 16;
    const float* bbase = Bz + (n0 + brow);

    auto bload = [&](int kk, uint4* bh, uint4* bm, uint4* bl) {
        float vb[16];
        const float* bp = bbase + (long)(kk + bk0) * N;
#pragma unroll
        for (int j = 0; j < 16; j++) vb[j] = bp[(long)j * N];
        split8(vb,     bh[0], bm[0], bl[0]);
        split8(vb + 8, bh[1], bm[1], bl[1]);
    };
    auto bwrite = [&](int buf, const uint4* bh, const uint4* bm, const uint4* bl) {
        *(uint4*)&Bs[buf][0][brow][bk0]     = bh[0];
        *(uint4*)&Bs[buf][0][brow][bk0 + 8] = bh[1];
        *(uint4*)&Bs[buf][1][brow][bk0]     = bm[0];
        *(uint4*)&Bs[buf][1][brow][bk0 + 8] = bm[1];
        *(uint4*)&Bs[buf][2][brow][bk0]     = bl[0];
        *(uint4*)&Bs[buf][2][brow][bk0 + 8] = bl[1];
    };
    auto aload = [&](int kk, short8* fah, short8* fam, short8* fal) {
#pragma unroll
        for (int r = 0; r < 4; r++) {
            float va[8] = {0.f, 0.f, 0.f, 0.f, 0.f, 0.f, 0.f, 0.f};
            if (aptr[r]) {
                float4 f0 = *(const float4*)(aptr[r] + kk);
                float4 f1 = *(const float4*)(aptr[r] + kk + 4);
                va[0] = f0.x; va[1] = f0.y; va[2] = f0.z; va[3] = f0.w;
                va[4] = f1.x; va[5] = f1.y; va[6] = f1.z; va[7] = f1.w;
            }
            uint4 hh, mm, ll;
            split8(va, hh, mm, ll);
            fah[r] = u2s8(hh); fam[r] = u2s8(mm); fal[r] = u2s8(ll);
        }
    };
    auto domfma = [&](int buf, const short8* fah, const short8* fam, const short8* fal) {
#pragma unroll
        for (int c = 0; c < 4; c++) {
            short8 fbh = *(const short8*)&Bs[buf][0][wn + 16 * c + ln][lq * 8];
            short8 fbm = *(const short8*)&Bs[buf][1][wn + 16 * c + ln][lq * 8];
            short8 fbl = *(const short8*)&Bs[buf][2][wn + 16 * c + ln][lq * 8];
#pragma unroll
            for (int r = 0; r < 4; r++) {
                f32x4 a2 = acc[r][c];
                a2 = __builtin_amdgcn_mfma_f32_16x16x32_bf16(fah[r], fbh, a2, 0, 0, 0);
                a2 = __builtin_amdgcn_mfma_f32_16x16x32_bf16(fah[r], fbm, a2, 0, 0, 0);
                a2 = __builtin_amdgcn_mfma_f32_16x16x32_bf16(fam[r], fbh, a2, 0, 0, 0);
                a2 = __builtin_amdgcn_mfma_f32_16x16x32_bf16(fah[r], fbl, a2, 0, 0, 0);
                a2 = __builtin_amdgcn_mfma_f32_16x16x32_bf16(fam[r], fbm, a2, 0, 0, 0);
                a2 = __builtin_amdgcn_mfma_f32_16x16x32_bf16(fal[r], fbh, a2, 0, 0, 0);
                acc[r][c] = a2;
            }
        }
    };

    // prologue: stage B(k=0) into buf0
    {
        uint4 bh[2], bm[2], bl[2];
        bload(0, bh, bm, bl);
        bwrite(0, bh, bm, bl);
    }
    __syncthreads();

    for (int k0 = 0; k0 < K; k0 += 64) {
        short8 fah[4], fam[4], fal[4];
        uint4 bh[2], bm[2], bl[2];
        // phase 0: compute buf0 @k0, prefetch buf1 @k0+32 (always valid: K%64==0)
        aload(k0, fah, fam, fal);
        bload(k0 + 32, bh, bm, bl);
        domfma(0, fah, fam, fal);
        bwrite(1, bh, bm, bl);
        __syncthreads();
        // phase 1: compute buf1 @k0+32, prefetch buf0 @k0+64
        aload(k0 + 32, fah, fam, fal);
        int kn = k0 + 64;
        bool more = kn < K;
        if (more) bload(kn, bh, bm, bl);
        domfma(1, fah, fam, fal);
        if (more) bwrite(0, bh, bm, bl);
        __syncthreads();
    }

    // C/D: col=lane&15, row=(lane>>4)*4+i  [m89-verified]
#pragma unroll
    for (int r = 0; r < 4; r++)
#pragma unroll
        for (int c = 0; c < 4; c++) {
            int rowb = wm + 16 * r + lq * 4;
            int col  = n0 + wn + 16 * c + ln;
#pragma unroll
            for (int i = 0; i < 4; i++) {
                int p = p0 + rowb + i;
                if (p >= me) continue;
                if (EPI == 2) {
                    atomicAdd(hout + (long)rows[p] * N + col, rwgt[p] * acc[r][c][i]);
                } else if (EPI == 1) {
                    float* cp = Cz + (long)p * N + col;
                    *cp += acc[r][c][i];
                } else {
                    Cz[(long)p * N + col] = acc[r][c][i];
                }
            }
        }
}

// ---------------- split-bf16 MFMA flash attention ----------------
__global__ __launch_bounds__(256) void k_attn_mfma(const float* __restrict__ q,
                                                   const float* __restrict__ k,
                                                   const float* __restrict__ v,
                                                   float* __restrict__ o) {
    int head = blockIdx.y;
    int qi = ((blockIdx.y >> 3) & 1) ? (int)(gridDim.x - 1 - blockIdx.x) : (int)blockIdx.x;
    int q0 = qi * 64;

    __shared__ __align__(16) unsigned short Ks[3][64][72];  // [plane][kv][d]
    __shared__ __align__(16) unsigned short Vt[3][64][72];  // [plane][d][kv]
    __shared__ __align__(16) float Ps[64][68];              // [q][kv] fp32

    int t = threadIdx.x;
    int lane = t & 63, w = t >> 6;
    int ln = lane & 15, lq = lane >> 4;

    short8 qh[2], qm[2], qlr[2];
    {
        const float* qp = q + ((long)(q0 + 16 * w + ln) * H_ + head) * HD_;
#pragma unroll
        for (int ks = 0; ks < 2; ks++) {
            float vq[8];
            float4 f0 = *(const float4*)(qp + 32 * ks + lq * 8);
            float4 f1 = *(const float4*)(qp + 32 * ks + lq * 8 + 4);
            vq[0] = f0.x; vq[1] = f0.y; vq[2] = f0.z; vq[3] = f0.w;
            vq[4] = f1.x; vq[5] = f1.y; vq[6] = f1.z; vq[7] = f1.w;
            uint4 hh, mm, ll;
            split8(vq, hh, mm, ll);
            qh[ks] = u2s8(hh); qm[ks] = u2s8(mm); qlr[ks] = u2s8(ll);
        }
    }

    f32x4 oc[4];
    f32x4 zero4 = {0.f, 0.f, 0.f, 0.f};
#pragma unroll
    for (int c = 0; c < 4; c++) oc[c] = zero4;
    float m_run[4], l_run[4];
#pragma unroll
    for (int i = 0; i < 4; i++) { m_run[i] = -3.402823466e38f; l_run[i] = 0.f; }

    for (int kt = 0; kt <= qi; kt++) {
        __syncthreads();
        {
            int kr = t >> 2, kq4 = (t & 3) * 16;
            const float* kp = k + ((long)(kt * 64 + kr) * H_ + head) * HD_ + kq4;
            float vk[16];
#pragma unroll
            for (int j = 0; j < 4; j++) {
                float4 f = *(const float4*)(kp + 4 * j);
                vk[4 * j + 0] = f.x; vk[4 * j + 1] = f.y;
                vk[4 * j + 2] = f.z; vk[4 * j + 3] = f.w;
            }
            uint4 h0, m0, l0, h1, m1, l1;
            split8(vk,     h0, m0, l0);
            split8(vk + 8, h1, m1, l1);
            *(uint4*)&Ks[0][kr][kq4]     = h0; *(uint4*)&Ks[0][kr][kq4 + 8] = h1;
            *(uint4*)&Ks[1][kr][kq4]     = m0; *(uint4*)&Ks[1][kr][kq4 + 8] = m1;
            *(uint4*)&Ks[2][kr][kq4]     = l0; *(uint4*)&Ks[2][kr][kq4 + 8] = l1;
            const float* vp = v + ((long)(kt * 64 + lane) * H_ + head) * HD_ + w * 16;
            float vvv[16];
#pragma unroll
            for (int j = 0; j < 4; j++) {
                float4 f = *(const float4*)(vp + 4 * j);
                vvv[4 * j + 0] = f.x; vvv[4 * j + 1] = f.y;
                vvv[4 * j + 2] = f.z; vvv[4 * j + 3] = f.w;
            }
#pragma unroll
            for (int j = 0; j < 16; j++) {
                float x = vvv[j];
                unsigned uu = __float_as_uint(x);
                unsigned hh = uu & 0xFFFF0000u;
                float rr = x - __uint_as_float(hh);
                unsigned mm2 = __float_as_uint(rr) & 0xFFFF0000u;
                float ss2 = rr - __uint_as_float(mm2);
                Vt[0][w * 16 + j][lane] = (unsigned short)(hh >> 16);
                Vt[1][w * 16 + j][lane] = (unsigned short)(mm2 >> 16);
                Vt[2][w * 16 + j][lane] = (unsigned short)(__float_as_uint(ss2) >> 16);
            }
        }
        __syncthreads();

        f32x4 sc[4];
#pragma unroll
        for (int c = 0; c < 4; c++) sc[c] = zero4;
#pragma unroll
        for (int ks = 0; ks < 2; ks++) {
#pragma unroll
            for (int c = 0; c < 4; c++) {
                const int co = 16 * c + ln, ko = 32 * ks + lq * 8;
                short8 bh = *(const short8*)&Ks[0][co][ko];
                short8 bm = *(const short8*)&Ks[1][co][ko];
                short8 bl = *(const short8*)&Ks[2][co][ko];
                f32x4 a2 = sc[c];
                a2 = __builtin_amdgcn_mfma_f32_16x16x32_bf16(qh[ks],  bh, a2, 0, 0, 0);
                a2 = __builtin_amdgcn_mfma_f32_16x16x32_bf16(qh[ks],  bm, a2, 0, 0, 0);
                a2 = __builtin_amdgcn_mfma_f32_16x16x32_bf16(qm[ks],  bh, a2, 0, 0, 0);
                a2 = __builtin_amdgcn_mfma_f32_16x16x32_bf16(qh[ks],  bl, a2, 0, 0, 0);
                a2 = __builtin_amdgcn_mfma_f32_16x16x32_bf16(qm[ks],  bm, a2, 0, 0, 0);
                a2 = __builtin_amdgcn_mfma_f32_16x16x32_bf16(qlr[ks], bh, a2, 0, 0, 0);
                sc[c] = a2;
            }
        }

#pragma unroll
        for (int i = 0; i < 4; i++) {
            int qg = q0 + 16 * w + 4 * lq + i;
            float mx = -3.402823466e38f;
#pragma unroll
            for (int c = 0; c < 4; c++) {
                int kvg = kt * 64 + 16 * c + ln;
                float s = sc[c][i] * 0.125f;
                s = (kvg <= qg) ? s : -3.402823466e38f;
                sc[c][i] = s;
                mx = fmaxf(mx, s);
            }
            mx = fmaxf(mx, __shfl_xor(mx, 1));
            mx = fmaxf(mx, __shfl_xor(mx, 2));
            mx = fmaxf(mx, __shfl_xor(mx, 4));
            mx = fmaxf(mx, __shfl_xor(mx, 8));
            float mn = fmaxf(m_run[i], mx);
            float al = expf(m_run[i] - mn);
            m_run[i] = mn;
            float sum = 0.f;
#pragma unroll
            for (int c = 0; c < 4; c++) {
                float e = expf(sc[c][i] - mn);
                Ps[16 * w + 4 * lq + i][16 * c + ln] = e;
                sum += e;
            }
            sum += __shfl_xor(sum, 1);
            sum += __shfl_xor(sum, 2);
            sum += __shfl_xor(sum, 4);
            sum += __shfl_xor(sum, 8);
            l_run[i] = l_run[i] * al + sum;
#pragma unroll
            for (int c = 0; c < 4; c++) oc[c][i] *= al;
        }

#pragma unroll
        for (int ks = 0; ks < 2; ks++) {
            float pv8[8];
            *(float4*)&pv8[0] = *(const float4*)&Ps[16 * w + ln][32 * ks + lq * 8];
            *(float4*)&pv8[4] = *(const float4*)&Ps[16 * w + ln][32 * ks + lq * 8 + 4];
            uint4 ph4, pm4, pl4;
            split8(pv8, ph4, pm4, pl4);
            short8 pah = u2s8(ph4), pam = u2s8(pm4), pal = u2s8(pl4);
#pragma unroll
            for (int c = 0; c < 4; c++) {
                const int co = 16 * c + ln, ko = 32 * ks + lq * 8;
                short8 bh = *(const short8*)&Vt[0][co][ko];
                short8 bm = *(const short8*)&Vt[1][co][ko];
                short8 bl = *(const short8*)&Vt[2][co][ko];
                f32x4 a2 = oc[c];
                a2 = __builtin_amdgcn_mfma_f32_16x16x32_bf16(pah, bh, a2, 0, 0, 0);
                a2 = __builtin_amdgcn_mfma_f32_16x16x32_bf16(pah, bm, a2, 0, 0, 0);
                a2 = __builtin_amdgcn_mfma_f32_16x16x32_bf16(pam, bh, a2, 0, 0, 0);
                a2 = __builtin_amdgcn_mfma_f32_16x16x32_bf16(pah, bl, a2, 0, 0, 0);
                a2 = __builtin_amdgcn_mfma_f32_16x16x32_bf16(pam, bm, a2, 0, 0, 0);
                a2 = __builtin_amdgcn_mfma_f32_16x16x32_bf16(pal, bh, a2, 0, 0, 0);
                oc[c] = a2;
            }
        }
    }

#pragma unroll
    for (int i = 0; i < 4; i++) {
        float invl = 1.0f / l_run[i];
        int qg = q0 + 16 * w + 4 * lq + i;
        float* op = o + ((long)qg * H_ + head) * HD_;
#pragma unroll
        for (int c = 0; c < 4; c++) op[16 * c + ln] = oc[c][i] * invl;
    }
}

// ---------------- router: gate logits, softmax-top2 (stable), counts --------
__global__ __launch_bounds__(256) void k_router(const float* __restrict__ x,
                                                const float* __restrict__ gw,
                                                int* __restrict__ idx, float* __restrict__ wgt,
                                                int* __restrict__ cnt) {
    int tok  = (blockIdx.x << 2) | (threadIdx.x >> 6);
    int lane = threadIdx.x & 63;
    float acc[8] = {0.f, 0.f, 0.f, 0.f, 0.f, 0.f, 0.f, 0.f};
    for (int i = 0; i < 16; i++) {
        int d = lane + i * 64;
        float xv = x[(long)tok * D_ + d];
        const float* gp = gw + (long)d * E_;
#pragma unroll
        for (int e = 0; e < 8; e++) acc[e] = fmaf(xv, gp[e], acc[e]);
    }
#pragma unroll
    for (int e = 0; e < 8; e++)
#pragma unroll
        for (int m = 32; m >= 1; m >>= 1) acc[e] += __shfl_xor(acc[e], m);
    if (lane == 0) {
        int i1 = 0; float m1 = acc[0];
        for (int e = 1; e < 8; e++) if (acc[e] > m1) { m1 = acc[e]; i1 = e; }
        int i2 = -1; float m2 = -3.402823466e38f;
        for (int e = 0; e < 8; e++) if (e != i1 && acc[e] > m2) { m2 = acc[e]; i2 = e; }
        float w1 = 1.0f / (1.0f + expf(m2 - m1));
        idx[tok * 2] = i1; idx[tok * 2 + 1] = i2;
        wgt[tok * 2] = w1; wgt[tok * 2 + 1] = 1.0f - w1;
        atomicAdd(&cnt[i1], 1);
        atomicAdd(&cnt[i2], 1);
    }
}

__global__ void k_offsets(const int* __restrict__ cnt, int* __restrict__ off) {
    if (threadIdx.x == 0) {
        int run = 0;
        for (int e = 0; e < 8; e++) { off[e] = run; run += cnt[e]; }
        off[8] = run;
    }
}

__global__ __launch_bounds__(256) void k_scatter(const int* __restrict__ idx,
                                                 const float* __restrict__ wgt,
                                                 const int* __restrict__ off,
                                                 int* __restrict__ fill,
                                                 int* __restrict__ rows,
                                                 float* __restrict__ rwgt) {
    int tok = blockIdx.x * 256 + threadIdx.x;
#pragma unroll
    for (int j = 0; j < 2; j++) {
        int e = idx[tok * 2 + j];
        int pos = off[e] + atomicAdd(&fill[e], 1);
        rows[pos] = tok;
        rwgt[pos] = wgt[tok * 2 + j];
    }
}

__global__ __launch_bounds__(256) void k_silumul(const float* __restrict__ g,
                                                 const float* __restrict__ u,
                                                 float* __restrict__ z) {
    long i = (long)(blockIdx.x * 256 + threadIdx.x) * 4;
    float4 gv = *(const float4*)(g + i);
    float4 uv = *(const float4*)(u + i);
    float4 zv;
    zv.x = gv.x / (1.f + expf(-gv.x)) * uv.x;
    zv.y = gv.y / (1.f + expf(-gv.y)) * uv.y;
    zv.z = gv.z / (1.f + expf(-gv.z)) * uv.z;
    zv.w = gv.w / (1.f + expf(-gv.w)) * uv.w;
    *(float4*)(z + i) = zv;
}

// ---------------- transpose + cast: out_w (1024,32000) f32 -> (32000,1024) bf16
__global__ __launch_bounds__(256) void k_transcast(const float* __restrict__ in,
                                                   unsigned short* __restrict__ out) {
    int c0 = blockIdx.x * 32;   // n
    int r0 = blockIdx.y * 32;   // k
    __shared__ __align__(16) float T[32][36];
    int t = threadIdx.x;
    {
        int row = t >> 3, cq = (t & 7) * 4;
        *(float4*)&T[row][cq] = *(const float4*)(in + (long)(r0 + row) * V_ + c0 + cq);
    }
    __syncthreads();
    {
        int n = t >> 3, kq = (t & 7) * 4;
        ushort4 u;
        u.x = f2bf(T[kq + 0][n]); u.y = f2bf(T[kq + 1][n]);
        u.z = f2bf(T[kq + 2][n]); u.w = f2bf(T[kq + 3][n]);
        *(ushort4*)(out + (long)(c0 + n) * D_ + r0 + kq) = u;
    }
}

// ---------------- bf16 MFMA GEMM for logits: C = A(2048,1024) @ BT(32000,1024)^T
// LDS-free: each lane loads its own MFMA fragments direct from global
// (A and BT are both K-contiguous); 2-deep ping-pong prefetch, no barriers.
// A (4MB) and the 256KB B-panels (shared by 16 co-running m-blocks) are L2/L3
// resident, so the LDS staging round-trip was pure overhead.
__global__ __launch_bounds__(256) void k_gemm_bf16(const unsigned short* __restrict__ A,
                                                   const unsigned short* __restrict__ BT,
                                                   float* __restrict__ C) {
    int m0 = blockIdx.x * 128, n0 = blockIdx.y * 128;
    int t = threadIdx.x;
    int lane = t & 63, wave = t >> 6;
    int wm = (wave >> 1) * 64, wn = (wave & 1) * 64;
    int ln = lane & 15, lq = lane >> 4;
    f32x4 acc[4][4];
    f32x4 zero4 = {0.f, 0.f, 0.f, 0.f};
#pragma unroll
    for (int r = 0; r < 4; r++)
#pragma unroll
        for (int c = 0; c < 4; c++) acc[r][c] = zero4;

    const unsigned short* ap[4];
    const unsigned short* bp[4];
#pragma unroll
    for (int r = 0; r < 4; r++) ap[r] = A  + (long)(m0 + wm + 16 * r + ln) * 1024 + lq * 8;
#pragma unroll
    for (int c = 0; c < 4; c++) bp[c] = BT + (long)(n0 + wn + 16 * c + ln) * 1024 + lq * 8;

    short8 a0[4], b0[4], a1[4], b1[4];
#pragma unroll
    for (int r = 0; r < 4; r++) a0[r] = *(const short8*)(ap[r]);
#pragma unroll
    for (int c = 0; c < 4; c++) b0[c] = *(const short8*)(bp[c]);

#pragma unroll 1
    for (int k0 = 0; k0 < 1024; k0 += 64) {
        int k1 = k0 + 32;
#pragma unroll
        for (int r = 0; r < 4; r++) a1[r] = *(const short8*)(ap[r] + k1);
#pragma unroll
        for (int c = 0; c < 4; c++) b1[c] = *(const short8*)(bp[c] + k1);
#pragma unroll
        for (int r = 0; r < 4; r++)
#pragma unroll
            for (int c = 0; c < 4; c++)
                acc[r][c] = __builtin_amdgcn_mfma_f32_16x16x32_bf16(a0[r], b0[c], acc[r][c], 0, 0, 0);
        int k2 = (k0 + 64) & 1023;   // wrap on last iter: loaded values unused
#pragma unroll
        for (int r = 0; r < 4; r++) a0[r] = *(const short8*)(ap[r] + k2);
#pragma unroll
        for (int c = 0; c < 4; c++) b0[c] = *(const short8*)(bp[c] + k2);
#pragma unroll
        for (int r = 0; r < 4; r++)
#pragma unroll
            for (int c = 0; c < 4; c++)
                acc[r][c] = __builtin_amdgcn_mfma_f32_16x16x32_bf16(a1[r], b1[c], acc[r][c], 0, 0, 0);
    }

#pragma unroll
    for (int r = 0; r < 4; r++)
#pragma unroll
        for (int c = 0; c < 4; c++) {
            int row = m0 + wm + 16 * r + lq * 4;   // C/D: col=lane&15, row=(lane>>4)*4+i
            int col = n0 + wn + 16 * c + ln;
#pragma unroll
            for (int i = 0; i < 4; i++)
                C[(long)(row + i) * V_ + col] = acc[r][c][i];
        }
}

// ---------------- host ----------------
extern "C" void kernel_launch(void* const* d_in, const int* in_sizes, int n_in,
                              void* d_out, int out_size, void* d_ws, size_t ws_size,
                              hipStream_t stream) {
    (void)in_sizes; (void)n_in; (void)out_size; (void)ws_size;
    const int*   ids   = (const int*)d_in[0];
    const float* embed = (const float*)d_in[1];
    const float* wq    = (const float*)d_in[2];
    const float* wk    = (const float*)d_in[3];
    const float* wv    = (const float*)d_in[4];
    const float* wo    = (const float*)d_in[5];
    const float* qnw   = (const float*)d_in[6];
    const float* knw   = (const float*)d_in[7];
    const float* anw   = (const float*)d_in[8];
    const float* fnw   = (const float*)d_in[9];
    const float* gatew = (const float*)d_in[10];
    const float* wgate = (const float*)d_in[11];
    const float* wup   = (const float*)d_in[12];
    const float* wdown = (const float*)d_in[13];
    const float* finw  = (const float*)d_in[14];
    const float* outw  = (const float*)d_in[15];
    const float* cosb  = (const float*)d_in[16];
    const float* sinb  = (const float*)d_in[17];
    float* out = (float*)d_out;

    char* w = (char*)d_ws;
    float* h  = (float*)(w);
    float* x  = (float*)(w + 8388608);
    float* q  = (float*)(w + 16777216);
    float* kk = (float*)(w + 25165824);
    float* vv = (float*)(w + 33554432);
    float* ao = (float*)(w + 41943040);
    float* g  = (float*)(w + 50331648);
    float* u  = (float*)(w + 62914560);
    float* z  = (float*)(w + 75497472);
    unsigned short* hn  = (unsigned short*)(w + 88080384);
    unsigned short* owT = (unsigned short*)(w + 16777216);  // overlays q..z (dead by then)
    char* rbase = w + 92274688;
    int*   idx  = (int*)(rbase);
    float* wgt  = (float*)(rbase + 16384);
    int*   cnt  = (int*)(rbase + 32768);
    int*   fill = (int*)(rbase + 32768 + 32);
    int*   offs = (int*)(rbase + 32768 + 64);
    int*   rows = (int*)(rbase + 32768 + 128);
    float* rwgt = (float*)(rbase + 32768 + 128 + 16384);

    k_gather<<<2048, 256, 0, stream>>>(ids, embed, h);

    for (int l = 0; l < 2; l++) {
        const float* wq_l = wq + (long)l * D_ * D_;
        const float* wk_l = wk + (long)l * D_ * D_;
        const float* wv_l = wv + (long)l * D_ * D_;
        const float* wo_l = wo + (long)l * D_ * D_;
        const float* an_l = anw + l * D_;
        const float* fn_l = fnw + l * D_;
        const float* qn_l = qnw + l * HD_;
        const float* kn_l = knw + l * HD_;
        const float* gw_l = gatew + (long)l * D_ * E_;
        const float* wg_l = wgate + (long)l * E_ * D_ * MF_;
        const float* wu_l = wup   + (long)l * E_ * D_ * MF_;
        const float* wd_l = wdown + (long)l * E_ * MF_ * D_;

        k_rmsnorm<0><<<2048, 256, 0, stream>>>(h, an_l, x, nullptr);
        k_gemm_s6<0, 0><<<dim3(8, 16, 3), 256, 0, stream>>>(x, wq_l, wk_l, wv_l, q,
            nullptr, nullptr, nullptr, nullptr, 2048, 1024, 1024, 0, 2048L * 1024);
        k_qkrope<<<16384, 256, 0, stream>>>(q, kk, qn_l, kn_l, cosb, sinb);
        k_attn_mfma<<<dim3(32, 16), 256, 0, stream>>>(q, kk, vv, ao);
        k_gemm_s6<0, 1><<<dim3(8, 16, 1), 256, 0, stream>>>(ao, wo_l, nullptr, nullptr, h,
            nullptr, nullptr, nullptr, nullptr, 2048, 1024, 1024, 0, 0);
        k_rmsnorm<0><<<2048, 256, 0, stream>>>(h, fn_l, x, nullptr);
        hipMemsetAsync(cnt, 0, 64, stream);
        k_router<<<512, 256, 0, stream>>>(x, gw_l, idx, wgt, cnt);
        k_offsets<<<1, 64, 0, stream>>>(cnt, offs);
        k_scatter<<<8, 256, 0, stream>>>(idx, wgt, offs, fill, rows, rwgt);
        k_gemm_s6<1, 0><<<dim3(6, 16, 8), 256, 0, stream>>>(x, wg_l, nullptr, nullptr, g,
            offs, rows, nullptr, nullptr, 4096, 768, 1024, (long)D_ * MF_, 0);
        k_gemm_s6<1, 0><<<dim3(6, 16, 8), 256, 0, stream>>>(x, wu_l, nullptr, nullptr, u,
            offs, rows, nullptr, nullptr, 4096, 768, 1024, (long)D_ * MF_, 0);
        k_silumul<<<3072, 256, 0, stream>>>(g, u, z);
        k_gemm_s6<0, 2><<<dim3(8, 16, 8), 256, 0, stream>>>(z, wd_l, nullptr, nullptr, nullptr,
            offs, rows, rwgt, h, 4096, 1024, 768, (long)MF_ * D_, 0);
    }

    k_rmsnorm<1><<<2048, 256, 0, stream>>>(h, finw, nullptr, hn);
    k_transcast<<<dim3(1000, 32), 256, 0, stream>>>(outw, owT);
    k_gemm_bf16<<<dim3(16, 250), 256, 0, stream>>>(hn, owT, out);
}

// Round 4
// 2723.751 us; speedup vs baseline: 1.2248x; 1.2248x over previous
//
#include <hip/hip_runtime.h>
#include <hip/hip_bf16.h>

// Qwen3-MoE forward, MI355X. Router-critical math is fp32-faithful: dense GEMMs
// AND attention run on the bf16 MFMA pipe via an EXACT 3-plane bf16 split
// (x == xh+xm+xl, truncation split, 6 cross products -> rel err ~1e-7).
// R4: revert R3's latency-poisoned direct-global fragments (MfmaUtil 10%,
// occupancy 22%); back to R2's coalesced-LDS staging. New: weights are
// pre-split into 3 bf16 planes [n][k] once per layer (k_wsplit), removing the
// per-block B gather (16 strided scalar loads) + B split VALU from the GEMM
// hot loop. Plane values bit-identical to in-kernel split.

constexpr int S_ = 2048, D_ = 1024, H_ = 16, HD_ = 64, E_ = 8, MF_ = 768, V_ = 32000;

typedef short  short8 __attribute__((ext_vector_type(8)));
typedef float  f32x4  __attribute__((ext_vector_type(4)));

static __device__ __forceinline__ unsigned short f2bf(float f) {
    unsigned u = __float_as_uint(f);
    u += 0x7FFF + ((u >> 16) & 1);          // RNE
    return (unsigned short)(u >> 16);
}

static __device__ __forceinline__ short8 u2s8(uint4 u) {
    union { uint4 a; short8 b; } x; x.a = u; return x.b;
}

// ---------------- embed gather ----------------
__global__ __launch_bounds__(256) void k_gather(const int* __restrict__ ids,
                                                const float* __restrict__ emb,
                                                float* __restrict__ h) {
    int tok = blockIdx.x;
    int id  = ids[tok];
    const float4* src = (const float4*)(emb + (long)id * D_);
    float4*       dst = (float4*)(h + (long)tok * D_);
    dst[threadIdx.x] = src[threadIdx.x];
}

// ---------------- rmsnorm (row per block) ----------------
template <int BF>
__global__ __launch_bounds__(256) void k_rmsnorm(const float* __restrict__ in,
                                                 const float* __restrict__ w,
                                                 float* __restrict__ outf,
                                                 unsigned short* __restrict__ outb) {
    int row = blockIdx.x, t = threadIdx.x;
    float4 x = ((const float4*)(in + (long)row * D_))[t];
    float ss = x.x * x.x + x.y * x.y + x.z * x.z + x.w * x.w;
#pragma unroll
    for (int m = 32; m >= 1; m >>= 1) ss += __shfl_xor(ss, m);
    __shared__ float ps[4];
    if ((t & 63) == 0) ps[t >> 6] = ss;
    __syncthreads();
    float tot   = ps[0] + ps[1] + ps[2] + ps[3];
    float scale = 1.0f / sqrtf(tot * (1.0f / D_) + 1e-6f);
    float4 wv = ((const float4*)w)[t];
    float4 o;
    o.x = x.x * scale * wv.x; o.y = x.y * scale * wv.y;
    o.z = x.z * scale * wv.z; o.w = x.w * scale * wv.w;
    if (BF) {
        ushort4 ub;
        ub.x = f2bf(o.x); ub.y = f2bf(o.y); ub.z = f2bf(o.z); ub.w = f2bf(o.w);
        *(ushort4*)(outb + (long)row * D_ + t * 4) = ub;
    } else {
        ((float4*)(outf + (long)row * D_))[t] = o;
    }
}

// ---------------- per-head RMSNorm + RoPE (one wave per (tensor,tok,head)) ----
__global__ __launch_bounds__(256) void k_qkrope(float* __restrict__ q, float* __restrict__ k,
                                                const float* __restrict__ qn,
                                                const float* __restrict__ kn,
                                                const float* __restrict__ cosb,
                                                const float* __restrict__ sinb) {
    int wid  = (blockIdx.x << 2) | (threadIdx.x >> 6);   // 0 .. 65535
    int lane = threadIdx.x & 63;
    int tensor = wid >> 15;
    int rem    = wid & 32767;
    int tok = rem >> 4, head = rem & 15;
    float* ptr = tensor ? k : q;
    const float* nw = tensor ? kn : qn;
    long off = ((long)tok * H_ + head) * HD_ + lane;
    float v = ptr[off];
    float ss = v * v;
#pragma unroll
    for (int m = 32; m >= 1; m >>= 1) ss += __shfl_xor(ss, m);
    float xn = v * (1.0f / sqrtf(ss * (1.0f / HD_) + 1e-6f)) * nw[lane];
    float other = __shfl_xor(xn, 32);
    float rot = (lane < 32) ? -other : other;
    ptr[off] = xn * cosb[tok * HD_ + lane] + rot * sinb[tok * HD_ + lane];
}

// ---------------- exact 3-plane bf16 split helpers ----------------
static __device__ __forceinline__ void splitpack2(float x0, float x1,
                                                  unsigned& wh, unsigned& wm,
                                                  unsigned& wl) {
    unsigned u0 = __float_as_uint(x0), u1 = __float_as_uint(x1);
    unsigned h0 = u0 & 0xFFFF0000u,    h1 = u1 & 0xFFFF0000u;
    float r0 = x0 - __uint_as_float(h0), r1 = x1 - __uint_as_float(h1);
    unsigned m0 = __float_as_uint(r0) & 0xFFFF0000u;
    unsigned m1 = __float_as_uint(r1) & 0xFFFF0000u;
    float s0 = r0 - __uint_as_float(m0), s1 = r1 - __uint_as_float(m1);
    unsigned l0 = __float_as_uint(s0),   l1 = __float_as_uint(s1);
    wh = (h0 >> 16) | h1;
    wm = (m0 >> 16) | m1;
    wl = (l0 >> 16) | (l1 & 0xFFFF0000u);
}

static __device__ __forceinline__ void split8(const float* v,
                                              uint4& qh, uint4& qm, uint4& ql) {
    unsigned ph[4], pm[4], pl[4];
#pragma unroll
    for (int j = 0; j < 4; j++) splitpack2(v[2 * j], v[2 * j + 1], ph[j], pm[j], pl[j]);
    qh = make_uint4(ph[0], ph[1], ph[2], ph[3]);
    qm = make_uint4(pm[0], pm[1], pm[2], pm[3]);
    ql = make_uint4(pl[0], pl[1], pl[2], pl[3]);
}

// ---------------- weight pre-split: fp32 [K][N] -> 3 bf16 planes [N][K] -------
// out layout: [z][plane 0..2][N][K] shorts, z stride = outStrideZ (=3*N*K).
__global__ __launch_bounds__(256) void k_wsplit(const float* __restrict__ in,
                                                unsigned short* __restrict__ out,
                                                int N, int K,
                                                long inStrideZ, long outStrideZ) {
    int z = blockIdx.z;
    const float* inz = in + (long)z * inStrideZ;
    unsigned short* outz = out + (long)z * outStrideZ;
    int n0 = blockIdx.x * 32, k0 = blockIdx.y * 32;
    __shared__ float T[32][33];
    int t = threadIdx.x;
    {
        int row = t >> 3, c4 = (t & 7) * 4;   // row = k-in-tile
        *(float4*)&T[row][c4] = *(const float4*)(inz + (long)(k0 + row) * N + n0 + c4);
    }
    __syncthreads();
    int n = t >> 3, kq = (t & 7) * 4;
    float v0 = T[kq][n], v1 = T[kq + 1][n], v2 = T[kq + 2][n], v3 = T[kq + 3][n];
    unsigned h01, m01, l01, h23, m23, l23;
    splitpack2(v0, v1, h01, m01, l01);
    splitpack2(v2, v3, h23, m23, l23);
    long base = (long)(n0 + n) * K + k0 + kq;
    long pk = (long)N * K;
    *(uint2*)(outz + base)          = make_uint2(h01, h23);
    *(uint2*)(outz + pk + base)     = make_uint2(m01, m23);
    *(uint2*)(outz + 2 * pk + base) = make_uint2(l01, l23);
}

// ---------------- split-bf16 MFMA GEMM: C[M,N] = A[M,K] @ B[K,N] ----------------
// A fp32 [m][k]: loaded coalesced, split in regs, staged to LDS planes (R2).
// B: PRE-SPLIT bf16 planes [z][3][N][K]; staged to LDS with 6 uint4 loads/thread,
//    zero split VALU. z < zsplit -> BplA + z*3NK, else BplB + (z-zsplit)*3NK.
// IND: A rows via rows[]. EPI: 0 store, 1 residual add, 2 scaled atomic scatter.
template <int IND, int EPI>
__global__ __launch_bounds__(256) void k_gemm_s6(const float* __restrict__ A,
                                                 const unsigned short* __restrict__ BplA,
                                                 const unsigned short* __restrict__ BplB,
                                                 int zsplit,
                                                 float* __restrict__ C,
                                                 const int* __restrict__ offs,
                                                 const int* __restrict__ rows,
                                                 const float* __restrict__ rwgt,
                                                 float* __restrict__ hout,
                                                 int Mtot, int N, int K,
                                                 long cStrideZ) {
    int z = blockIdx.z;
    int ms, me;
    if (offs) { ms = offs[z]; me = offs[z + 1]; }
    else      { ms = 0; me = Mtot; }
    int p0 = ms + blockIdx.y * 128;
    if (p0 >= me) return;
    long planeSz = (long)N * K;
    const unsigned short* bpl = (z < zsplit) ? BplA + (long)z * 3 * planeSz
                                             : BplB + (long)(z - zsplit) * 3 * planeSz;
    float* Cz = C ? (C + (long)z * cStrideZ) : nullptr;
    int n0 = blockIdx.x * 128;

    __shared__ __align__(16) unsigned short As[3][128][40];  // planes h/m/l, [m][k]
    __shared__ __align__(16) unsigned short Bs[3][128][40];  // planes h/m/l, [n][k]

    int t = threadIdx.x;
    int lane = t & 63, wave = t >> 6;
    int wm = (wave >> 1) * 64, wn = (wave & 1) * 64;
    int ln = lane & 15, lq = lane >> 4;

    f32x4 acc[4][4];
    f32x4 zero4 = {0.f, 0.f, 0.f, 0.f};
#pragma unroll
    for (int r = 0; r < 4; r++)
#pragma unroll
        for (int c = 0; c < 4; c++) acc[r][c] = zero4;

    // A staging: thread -> row t>>1, k-half (t&1)*16
    int arow = t >> 1, ak0 = (t & 1) * 8;    // ak0 in shorts*? (floats: (t&1)*8? keep 16-float half)
    arow = t >> 1; int akf = (t & 1) * 16;   // 16 floats per half
    const float* aptr = nullptr;
    {
        int pA = p0 + arow;
        if (pA < me) {
            int srow = IND ? rows[pA] : pA;
            aptr = A + (long)srow * K + akf;
        }
    }
    (void)ak0;

    // B staging: 6 uint4 chunks per thread from pre-split planes.
    // chunk id = t + 256*j: plane = id>>9, rem = id&511, row = rem>>2, q = rem&3
    const unsigned short* bsrc[6];
    unsigned short* bdst[6];
#pragma unroll
    for (int j = 0; j < 6; j++) {
        int id = t + 256 * j;
        int plane = id >> 9, rem = id & 511;
        int brow = rem >> 2, bq = rem & 3;
        bsrc[j] = bpl + (long)plane * planeSz + (long)(n0 + brow) * K + bq * 8;
        bdst[j] = &Bs[plane][brow][bq * 8];
    }

    for (int k0 = 0; k0 < K; k0 += 32) {
        // ---- load + split A (16 floats -> 3 planes x 2 uint4), load B chunks
        float va[16];
        if (aptr) {
#pragma unroll
            for (int c4 = 0; c4 < 4; c4++) {
                float4 f = *(const float4*)(aptr + k0 + c4 * 4);
                va[c4 * 4 + 0] = f.x; va[c4 * 4 + 1] = f.y;
                va[c4 * 4 + 2] = f.z; va[c4 * 4 + 3] = f.w;
            }
        } else {
#pragma unroll
            for (int j = 0; j < 16; j++) va[j] = 0.f;
        }
        uint4 ah0, am0, al0, ah1, am1, al1;
        split8(va,     ah0, am0, al0);
        split8(va + 8, ah1, am1, al1);
        uint4 bv[6];
#pragma unroll
        for (int j = 0; j < 6; j++) bv[j] = *(const uint4*)(bsrc[j] + k0);

        __syncthreads();   // previous tile fully consumed
        *(uint4*)&As[0][arow][akf]     = ah0;
        *(uint4*)&As[0][arow][akf + 8] = ah1;
        *(uint4*)&As[1][arow][akf]     = am0;
        *(uint4*)&As[1][arow][akf + 8] = am1;
        *(uint4*)&As[2][arow][akf]     = al0;
        *(uint4*)&As[2][arow][akf + 8] = al1;
#pragma unroll
        for (int j = 0; j < 6; j++) *(uint4*)bdst[j] = bv[j];
        __syncthreads();

        short8 fah[4], fam[4], fal[4];
#pragma unroll
        for (int r = 0; r < 4; r++) {
            fah[r] = *(const short8*)&As[0][wm + 16 * r + ln][lq * 8];
            fam[r] = *(const short8*)&As[1][wm + 16 * r + ln][lq * 8];
            fal[r] = *(const short8*)&As[2][wm + 16 * r + ln][lq * 8];
        }
#pragma unroll
        for (int c = 0; c < 4; c++) {
            short8 fbh = *(const short8*)&Bs[0][wn + 16 * c + ln][lq * 8];
            short8 fbm = *(const short8*)&Bs[1][wn + 16 * c + ln][lq * 8];
            short8 fbl = *(const short8*)&Bs[2][wn + 16 * c + ln][lq * 8];
#pragma unroll
            for (int r = 0; r < 4; r++) {
                f32x4 a2 = acc[r][c];
                a2 = __builtin_amdgcn_mfma_f32_16x16x32_bf16(fah[r], fbh, a2, 0, 0, 0);
                a2 = __builtin_amdgcn_mfma_f32_16x16x32_bf16(fah[r], fbm, a2, 0, 0, 0);
                a2 = __builtin_amdgcn_mfma_f32_16x16x32_bf16(fam[r], fbh, a2, 0, 0, 0);
                a2 = __builtin_amdgcn_mfma_f32_16x16x32_bf16(fah[r], fbl, a2, 0, 0, 0);
                a2 = __builtin_amdgcn_mfma_f32_16x16x32_bf16(fam[r], fbm, a2, 0, 0, 0);
                a2 = __builtin_amdgcn_mfma_f32_16x16x32_bf16(fal[r], fbh, a2, 0, 0, 0);
                acc[r][c] = a2;
            }
        }
    }

    // C/D: col=lane&15, row=(lane>>4)*4+i  [m89-verified]
#pragma unroll
    for (int r = 0; r < 4; r++)
#pragma unroll
        for (int c = 0; c < 4; c++) {
            int rowb = wm + 16 * r + lq * 4;
            int col  = n0 + wn + 16 * c + ln;
#pragma unroll
            for (int i = 0; i < 4; i++) {
                int p = p0 + rowb + i;
                if (p >= me) continue;
                if (EPI == 2) {
                    atomicAdd(hout + (long)rows[p] * N + col, rwgt[p] * acc[r][c][i]);
                } else if (EPI == 1) {
                    float* cp = Cz + (long)p * N + col;
                    *cp += acc[r][c][i];
                } else {
                    Cz[(long)p * N + col] = acc[r][c][i];
                }
            }
        }
}

// ---------------- split-bf16 MFMA flash attention (R2, unchanged) ----------------
__global__ __launch_bounds__(256) void k_attn_mfma(const float* __restrict__ q,
                                                   const float* __restrict__ k,
                                                   const float* __restrict__ v,
                                                   float* __restrict__ o) {
    int head = blockIdx.y;
    int qi = ((blockIdx.y >> 3) & 1) ? (int)(gridDim.x - 1 - blockIdx.x) : (int)blockIdx.x;
    int q0 = qi * 64;

    __shared__ __align__(16) unsigned short Ks[3][64][72];  // [plane][kv][d]
    __shared__ __align__(16) unsigned short Vt[3][64][72];  // [plane][d][kv]
    __shared__ __align__(16) float Ps[64][68];              // [q][kv] fp32

    int t = threadIdx.x;
    int lane = t & 63, w = t >> 6;
    int ln = lane & 15, lq = lane >> 4;

    short8 qh[2], qm[2], qlr[2];
    {
        const float* qp = q + ((long)(q0 + 16 * w + ln) * H_ + head) * HD_;
#pragma unroll
        for (int ks = 0; ks < 2; ks++) {
            float vq[8];
            float4 f0 = *(const float4*)(qp + 32 * ks + lq * 8);
            float4 f1 = *(const float4*)(qp + 32 * ks + lq * 8 + 4);
            vq[0] = f0.x; vq[1] = f0.y; vq[2] = f0.z; vq[3] = f0.w;
            vq[4] = f1.x; vq[5] = f1.y; vq[6] = f1.z; vq[7] = f1.w;
            uint4 hh, mm, ll;
            split8(vq, hh, mm, ll);
            qh[ks] = u2s8(hh); qm[ks] = u2s8(mm); qlr[ks] = u2s8(ll);
        }
    }

    f32x4 oc[4];
    f32x4 zero4 = {0.f, 0.f, 0.f, 0.f};
#pragma unroll
    for (int c = 0; c < 4; c++) oc[c] = zero4;
    float m_run[4], l_run[4];
#pragma unroll
    for (int i = 0; i < 4; i++) { m_run[i] = -3.402823466e38f; l_run[i] = 0.f; }

    for (int kt = 0; kt <= qi; kt++) {
        __syncthreads();
        {
            int kr = t >> 2, kq4 = (t & 3) * 16;
            const float* kp = k + ((long)(kt * 64 + kr) * H_ + head) * HD_ + kq4;
            float vk[16];
#pragma unroll
            for (int j = 0; j < 4; j++) {
                float4 f = *(const float4*)(kp + 4 * j);
                vk[4 * j + 0] = f.x; vk[4 * j + 1] = f.y;
                vk[4 * j + 2] = f.z; vk[4 * j + 3] = f.w;
            }
            uint4 h0, m0, l0, h1, m1, l1;
            split8(vk,     h0, m0, l0);
            split8(vk + 8, h1, m1, l1);
            *(uint4*)&Ks[0][kr][kq4]     = h0; *(uint4*)&Ks[0][kr][kq4 + 8] = h1;
            *(uint4*)&Ks[1][kr][kq4]     = m0; *(uint4*)&Ks[1][kr][kq4 + 8] = m1;
            *(uint4*)&Ks[2][kr][kq4]     = l0; *(uint4*)&Ks[2][kr][kq4 + 8] = l1;
            const float* vp = v + ((long)(kt * 64 + lane) * H_ + head) * HD_ + w * 16;
            float vvv[16];
#pragma unroll
            for (int j = 0; j < 4; j++) {
                float4 f = *(const float4*)(vp + 4 * j);
                vvv[4 * j + 0] = f.x; vvv[4 * j + 1] = f.y;
                vvv[4 * j + 2] = f.z; vvv[4 * j + 3] = f.w;
            }
#pragma unroll
            for (int j = 0; j < 16; j++) {
                float x = vvv[j];
                unsigned uu = __float_as_uint(x);
                unsigned hh = uu & 0xFFFF0000u;
                float rr = x - __uint_as_float(hh);
                unsigned mm2 = __float_as_uint(rr) & 0xFFFF0000u;
                float ss2 = rr - __uint_as_float(mm2);
                Vt[0][w * 16 + j][lane] = (unsigned short)(hh >> 16);
                Vt[1][w * 16 + j][lane] = (unsigned short)(mm2 >> 16);
                Vt[2][w * 16 + j][lane] = (unsigned short)(__float_as_uint(ss2) >> 16);
            }
        }
        __syncthreads();

        f32x4 sc[4];
#pragma unroll
        for (int c = 0; c < 4; c++) sc[c] = zero4;
#pragma unroll
        for (int ks = 0; ks < 2; ks++) {
#pragma unroll
            for (int c = 0; c < 4; c++) {
                const int co = 16 * c + ln, ko = 32 * ks + lq * 8;
                short8 bh = *(const short8*)&Ks[0][co][ko];
                short8 bm = *(const short8*)&Ks[1][co][ko];
                short8 bl = *(const short8*)&Ks[2][co][ko];
                f32x4 a2 = sc[c];
                a2 = __builtin_amdgcn_mfma_f32_16x16x32_bf16(qh[ks],  bh, a2, 0, 0, 0);
                a2 = __builtin_amdgcn_mfma_f32_16x16x32_bf16(qh[ks],  bm, a2, 0, 0, 0);
                a2 = __builtin_amdgcn_mfma_f32_16x16x32_bf16(qm[ks],  bh, a2, 0, 0, 0);
                a2 = __builtin_amdgcn_mfma_f32_16x16x32_bf16(qh[ks],  bl, a2, 0, 0, 0);
                a2 = __builtin_amdgcn_mfma_f32_16x16x32_bf16(qm[ks],  bm, a2, 0, 0, 0);
                a2 = __builtin_amdgcn_mfma_f32_16x16x32_bf16(qlr[ks], bh, a2, 0, 0, 0);
                sc[c] = a2;
            }
        }

#pragma unroll
        for (int i = 0; i < 4; i++) {
            int qg = q0 + 16 * w + 4 * lq + i;
            float mx = -3.402823466e38f;
#pragma unroll
            for (int c = 0; c < 4; c++) {
                int kvg = kt * 64 + 16 * c + ln;
                float s = sc[c][i] * 0.125f;
                s = (kvg <= qg) ? s : -3.402823466e38f;
                sc[c][i] = s;
                mx = fmaxf(mx, s);
            }
            mx = fmaxf(mx, __shfl_xor(mx, 1));
            mx = fmaxf(mx, __shfl_xor(mx, 2));
            mx = fmaxf(mx, __shfl_xor(mx, 4));
            mx = fmaxf(mx, __shfl_xor(mx, 8));
            float mn = fmaxf(m_run[i], mx);
            float al = expf(m_run[i] - mn);
            m_run[i] = mn;
            float sum = 0.f;
#pragma unroll
            for (int c = 0; c < 4; c++) {
                float e = expf(sc[c][i] - mn);
                Ps[16 * w + 4 * lq + i][16 * c + ln] = e;
                sum += e;
            }
            sum += __shfl_xor(sum, 1);
            sum += __shfl_xor(sum, 2);
            sum += __shfl_xor(sum, 4);
            sum += __shfl_xor(sum, 8);
            l_run[i] = l_run[i] * al + sum;
#pragma unroll
            for (int c = 0; c < 4; c++) oc[c][i] *= al;
        }

#pragma unroll
        for (int ks = 0; ks < 2; ks++) {
            float pv8[8];
            *(float4*)&pv8[0] = *(const float4*)&Ps[16 * w + ln][32 * ks + lq * 8];
            *(float4*)&pv8[4] = *(const float4*)&Ps[16 * w + ln][32 * ks + lq * 8 + 4];
            uint4 ph4, pm4, pl4;
            split8(pv8, ph4, pm4, pl4);
            short8 pah = u2s8(ph4), pam = u2s8(pm4), pal = u2s8(pl4);
#pragma unroll
            for (int c = 0; c < 4; c++) {
                const int co = 16 * c + ln, ko = 32 * ks + lq * 8;
                short8 bh = *(const short8*)&Vt[0][co][ko];
                short8 bm = *(const short8*)&Vt[1][co][ko];
                short8 bl = *(const short8*)&Vt[2][co][ko];
                f32x4 a2 = oc[c];
                a2 = __builtin_amdgcn_mfma_f32_16x16x32_bf16(pah, bh, a2, 0, 0, 0);
                a2 = __builtin_amdgcn_mfma_f32_16x16x32_bf16(pah, bm, a2, 0, 0, 0);
                a2 = __builtin_amdgcn_mfma_f32_16x16x32_bf16(pam, bh, a2, 0, 0, 0);
                a2 = __builtin_amdgcn_mfma_f32_16x16x32_bf16(pah, bl, a2, 0, 0, 0);
                a2 = __builtin_amdgcn_mfma_f32_16x16x32_bf16(pam, bm, a2, 0, 0, 0);
                a2 = __builtin_amdgcn_mfma_f32_16x16x32_bf16(pal, bh, a2, 0, 0, 0);
                oc[c] = a2;
            }
        }
    }

#pragma unroll
    for (int i = 0; i < 4; i++) {
        float invl = 1.0f / l_run[i];
        int qg = q0 + 16 * w + 4 * lq + i;
        float* op = o + ((long)qg * H_ + head) * HD_;
#pragma unroll
        for (int c = 0; c < 4; c++) op[16 * c + ln] = oc[c][i] * invl;
    }
}

// ---------------- router: gate logits, softmax-top2 (stable), counts --------
__global__ __launch_bounds__(256) void k_router(const float* __restrict__ x,
                                                const float* __restrict__ gw,
                                                int* __restrict__ idx, float* __restrict__ wgt,
                                                int* __restrict__ cnt) {
    int tok  = (blockIdx.x << 2) | (threadIdx.x >> 6);
    int lane = threadIdx.x & 63;
    float acc[8] = {0.f, 0.f, 0.f, 0.f, 0.f, 0.f, 0.f, 0.f};
    for (int i = 0; i < 16; i++) {
        int d = lane + i * 64;
        float xv = x[(long)tok * D_ + d];
        const float* gp = gw + (long)d * E_;
#pragma unroll
        for (int e = 0; e < 8; e++) acc[e] = fmaf(xv, gp[e], acc[e]);
    }
#pragma unroll
    for (int e = 0; e < 8; e++)
#pragma unroll
        for (int m = 32; m >= 1; m >>= 1) acc[e] += __shfl_xor(acc[e], m);
    if (lane == 0) {
        int i1 = 0; float m1 = acc[0];
        for (int e = 1; e < 8; e++) if (acc[e] > m1) { m1 = acc[e]; i1 = e; }
        int i2 = -1; float m2 = -3.402823466e38f;
        for (int e = 0; e < 8; e++) if (e != i1 && acc[e] > m2) { m2 = acc[e]; i2 = e; }
        float w1 = 1.0f / (1.0f + expf(m2 - m1));
        idx[tok * 2] = i1; idx[tok * 2 + 1] = i2;
        wgt[tok * 2] = w1; wgt[tok * 2 + 1] = 1.0f - w1;
        atomicAdd(&cnt[i1], 1);
        atomicAdd(&cnt[i2], 1);
    }
}

__global__ void k_offsets(const int* __restrict__ cnt, int* __restrict__ off) {
    if (threadIdx.x == 0) {
        int run = 0;
        for (int e = 0; e < 8; e++) { off[e] = run; run += cnt[e]; }
        off[8] = run;
    }
}

__global__ __launch_bounds__(256) void k_scatter(const int* __restrict__ idx,
                                                 const float* __restrict__ wgt,
                                                 const int* __restrict__ off,
                                                 int* __restrict__ fill,
                                                 int* __restrict__ rows,
                                                 float* __restrict__ rwgt) {
    int tok = blockIdx.x * 256 + threadIdx.x;
#pragma unroll
    for (int j = 0; j < 2; j++) {
        int e = idx[tok * 2 + j];
        int pos = off[e] + atomicAdd(&fill[e], 1);
        rows[pos] = tok;
        rwgt[pos] = wgt[tok * 2 + j];
    }
}

__global__ __launch_bounds__(256) void k_silumul(const float* __restrict__ g,
                                                 const float* __restrict__ u,
                                                 float* __restrict__ z) {
    long i = (long)(blockIdx.x * 256 + threadIdx.x) * 4;
    float4 gv = *(const float4*)(g + i);
    float4 uv = *(const float4*)(u + i);
    float4 zv;
    zv.x = gv.x / (1.f + expf(-gv.x)) * uv.x;
    zv.y = gv.y / (1.f + expf(-gv.y)) * uv.y;
    zv.z = gv.z / (1.f + expf(-gv.z)) * uv.z;
    zv.w = gv.w / (1.f + expf(-gv.w)) * uv.w;
    *(float4*)(z + i) = zv;
}

// ---------------- transpose + cast: out_w (1024,32000) f32 -> (32000,1024) bf16
__global__ __launch_bounds__(256) void k_transcast(const float* __restrict__ in,
                                                   unsigned short* __restrict__ out) {
    int c0 = blockIdx.x * 32;   // n
    int r0 = blockIdx.y * 32;   // k
    __shared__ __align__(16) float T[32][36];
    int t = threadIdx.x;
    {
        int row = t >> 3, cq = (t & 7) * 4;
        *(float4*)&T[row][cq] = *(const float4*)(in + (long)(r0 + row) * V_ + c0 + cq);
    }
    __syncthreads();
    {
        int n = t >> 3, kq = (t & 7) * 4;
        ushort4 u;
        u.x = f2bf(T[kq + 0][n]); u.y = f2bf(T[kq + 1][n]);
        u.z = f2bf(T[kq + 2][n]); u.w = f2bf(T[kq + 3][n]);
        *(ushort4*)(out + (long)(c0 + n) * D_ + r0 + kq) = u;
    }
}

// ---------------- bf16 MFMA GEMM for logits (R2 LDS version, reverted) ---------
__global__ __launch_bounds__(256) void k_gemm_bf16(const unsigned short* __restrict__ A,
                                                   const unsigned short* __restrict__ BT,
                                                   float* __restrict__ C) {
    int m0 = blockIdx.x * 128, n0 = blockIdx.y * 128;
    __shared__ __align__(16) unsigned short As[128][40];
    __shared__ __align__(16) unsigned short Bs[128][40];
    int t = threadIdx.x;
    int lane = t & 63, wave = t >> 6;
    int wm = (wave >> 1) * 64, wn = (wave & 1) * 64;
    int ln = lane & 15, lq = lane >> 4;
    f32x4 acc[4][4];
    f32x4 zero4 = {0.f, 0.f, 0.f, 0.f};
#pragma unroll
    for (int r = 0; r < 4; r++)
#pragma unroll
        for (int c = 0; c < 4; c++) acc[r][c] = zero4;
    int rowA = t >> 1;
    int q1 = (t * 2) & 3, q2 = (t * 2 + 1) & 3;
    for (int k0 = 0; k0 < 1024; k0 += 32) {
        const uint4* ap = (const uint4*)(A + (long)(m0 + rowA) * 1024 + k0);
        const uint4* bp = (const uint4*)(BT + (long)(n0 + rowA) * 1024 + k0);
        uint4 a0 = ap[q1], a1 = ap[q2];
        uint4 b0 = bp[q1], b1 = bp[q2];
        __syncthreads();
        *(uint4*)&As[rowA][q1 * 8] = a0;
        *(uint4*)&As[rowA][q2 * 8] = a1;
        *(uint4*)&Bs[rowA][q1 * 8] = b0;
        *(uint4*)&Bs[rowA][q2 * 8] = b1;
        __syncthreads();
        short8 a[4], b[4];
#pragma unroll
        for (int r = 0; r < 4; r++) a[r] = *(const short8*)&As[wm + 16 * r + ln][lq * 8];
#pragma unroll
        for (int c = 0; c < 4; c++) b[c] = *(const short8*)&Bs[wn + 16 * c + ln][lq * 8];
#pragma unroll
        for (int r = 0; r < 4; r++)
#pragma unroll
            for (int c = 0; c < 4; c++)
                acc[r][c] = __builtin_amdgcn_mfma_f32_16x16x32_bf16(a[r], b[c], acc[r][c], 0, 0, 0);
    }
#pragma unroll
    for (int r = 0; r < 4; r++)
#pragma unroll
        for (int c = 0; c < 4; c++) {
            int row = m0 + wm + 16 * r + lq * 4;
            int col = n0 + wn + 16 * c + ln;
#pragma unroll
            for (int i = 0; i < 4; i++)
                C[(long)(row + i) * V_ + col] = acc[r][c][i];
        }
}

// ---------------- host ----------------
extern "C" void kernel_launch(void* const* d_in, const int* in_sizes, int n_in,
                              void* d_out, int out_size, void* d_ws, size_t ws_size,
                              hipStream_t stream) {
    (void)in_sizes; (void)n_in; (void)out_size; (void)ws_size;
    const int*   ids   = (const int*)d_in[0];
    const float* embed = (const float*)d_in[1];
    const float* wq    = (const float*)d_in[2];
    const float* wk    = (const float*)d_in[3];
    const float* wv    = (const float*)d_in[4];
    const float* wo    = (const float*)d_in[5];
    const float* qnw   = (const float*)d_in[6];
    const float* knw   = (const float*)d_in[7];
    const float* anw   = (const float*)d_in[8];
    const float* fnw   = (const float*)d_in[9];
    const float* gatew = (const float*)d_in[10];
    const float* wgate = (const float*)d_in[11];
    const float* wup   = (const float*)d_in[12];
    const float* wdown = (const float*)d_in[13];
    const float* finw  = (const float*)d_in[14];
    const float* outw  = (const float*)d_in[15];
    const float* cosb  = (const float*)d_in[16];
    const float* sinb  = (const float*)d_in[17];
    float* out = (float*)d_out;

    char* w = (char*)d_ws;
    float* h  = (float*)(w);                         // [0, 8M)
    float* x  = (float*)(w + 8388608);               // [8M, 16M)
    float* q  = (float*)(w + 16777216);              // [16M, 24M)
    float* kk = (float*)(w + 25165824);              // [24M, 32M)
    float* vv = (float*)(w + 33554432);              // [32M, 40M)
    float* ao = (float*)(w + 41943040);              // [40M, 48M)
    float* g  = (float*)(w + 50331648);              // [48M, 60M)
    float* u  = (float*)(w + 62914560);              // [60M, 72M)
    float* z  = (float*)(w + 75497472);              // [72M, 84M)
    unsigned short* hn  = (unsigned short*)(w + 88080384);
    unsigned short* owT = (unsigned short*)(w + 16777216);  // overlays q..z (dead by then)
    char* rbase = w + 92274688;
    int*   idx  = (int*)(rbase);
    float* wgt  = (float*)(rbase + 16384);
    int*   cnt  = (int*)(rbase + 32768);
    int*   fill = (int*)(rbase + 32768 + 32);
    int*   offs = (int*)(rbase + 32768 + 64);
    int*   rows = (int*)(rbase + 32768 + 128);
    float* rwgt = (float*)(rbase + 32768 + 128 + 16384);

    // weight-plane overlays (dead-region reuse; ws footprint unchanged):
    unsigned short* qkvpl = (unsigned short*)(w + 50331648); // 18.9MB over g/u-head (QKV gemm phase)
    unsigned short* wopl  = (unsigned short*)(w + 50331648); // 6.3MB  (after QKV gemm)
    unsigned short* mplA  = (unsigned short*)(w + 16777216); // 28.3MB over q/kk/vv/ao-head (experts 0-5, after wo gemm)
    unsigned short* wgplB = (unsigned short*)(w + 62914560); // 9.4MB over u      (experts 6-7 of wg)
    unsigned short* wuplB = (unsigned short*)(w + 75497472); // 9.4MB over z      (experts 6-7 of wu)
    unsigned short* wdplB = (unsigned short*)(w + 50331648); // 9.4MB over g      (experts 6-7 of wd, after silumul)

    const long DxD = (long)D_ * D_;          // 1M
    const long DxM = (long)D_ * MF_;         // per-expert fp32 elems (wg/wu)
    const long EPL_DM = 3L * MF_ * D_;       // plane-group stride (shorts) for N=768,K=1024 AND N=1024,K=768

    k_gather<<<2048, 256, 0, stream>>>(ids, embed, h);

    for (int l = 0; l < 2; l++) {
        const float* wq_l = wq + (long)l * DxD;
        const float* wk_l = wk + (long)l * DxD;
        const float* wv_l = wv + (long)l * DxD;
        const float* wo_l = wo + (long)l * DxD;
        const float* an_l = anw + l * D_;
        const float* fn_l = fnw + l * D_;
        const float* qn_l = qnw + l * HD_;
        const float* kn_l = knw + l * HD_;
        const float* gw_l = gatew + (long)l * D_ * E_;
        const float* wg_l = wgate + (long)l * E_ * DxM;
        const float* wu_l = wup   + (long)l * E_ * DxM;
        const float* wd_l = wdown + (long)l * E_ * DxM;

        k_rmsnorm<0><<<2048, 256, 0, stream>>>(h, an_l, x, nullptr);

        // -- QKV: pre-split wq/wk/wv -> qkvpl[z][3][1024][1024], fused GEMM
        k_wsplit<<<dim3(32, 32, 1), 256, 0, stream>>>(wq_l, qkvpl,             1024, 1024, 0, 0);
        k_wsplit<<<dim3(32, 32, 1), 256, 0, stream>>>(wk_l, qkvpl + 3 * DxD,   1024, 1024, 0, 0);
        k_wsplit<<<dim3(32, 32, 1), 256, 0, stream>>>(wv_l, qkvpl + 6 * DxD,   1024, 1024, 0, 0);
        k_gemm_s6<0, 0><<<dim3(8, 16, 3), 256, 0, stream>>>(x, qkvpl, qkvpl, 8, q,
            nullptr, nullptr, nullptr, nullptr, 2048, 1024, 1024, 2048L * 1024);

        // -- wo planes (qkvpl region dead now)
        k_wsplit<<<dim3(32, 32, 1), 256, 0, stream>>>(wo_l, wopl, 1024, 1024, 0, 0);

        k_qkrope<<<16384, 256, 0, stream>>>(q, kk, qn_l, kn_l, cosb, sinb);
        k_attn_mfma<<<dim3(32, 16), 256, 0, stream>>>(q, kk, vv, ao);
        k_gemm_s6<0, 1><<<dim3(8, 16, 1), 256, 0, stream>>>(ao, wopl, wopl, 8, h,
            nullptr, nullptr, nullptr, nullptr, 2048, 1024, 1024, 0);

        k_rmsnorm<0><<<2048, 256, 0, stream>>>(h, fn_l, x, nullptr);
        hipMemsetAsync(cnt, 0, 64, stream);
        k_router<<<512, 256, 0, stream>>>(x, gw_l, idx, wgt, cnt);
        k_offsets<<<1, 64, 0, stream>>>(cnt, offs);
        k_scatter<<<8, 256, 0, stream>>>(idx, wgt, offs, fill, rows, rwgt);

        // -- gate proj: wg planes (experts 0-5 -> mplA over q/kk/vv/ao; 6-7 -> over u)
        k_wsplit<<<dim3(24, 32, 6), 256, 0, stream>>>(wg_l,             mplA,  768, 1024, DxM, EPL_DM);
        k_wsplit<<<dim3(24, 32, 2), 256, 0, stream>>>(wg_l + 6 * DxM,   wgplB, 768, 1024, DxM, EPL_DM);
        k_gemm_s6<1, 0><<<dim3(6, 16, 8), 256, 0, stream>>>(x, mplA, wgplB, 6, g,
            offs, rows, nullptr, nullptr, 4096, 768, 1024, 0);

        // -- up proj: wu planes (0-5 -> mplA; 6-7 -> over z)
        k_wsplit<<<dim3(24, 32, 6), 256, 0, stream>>>(wu_l,             mplA,  768, 1024, DxM, EPL_DM);
        k_wsplit<<<dim3(24, 32, 2), 256, 0, stream>>>(wu_l + 6 * DxM,   wuplB, 768, 1024, DxM, EPL_DM);
        k_gemm_s6<1, 0><<<dim3(6, 16, 8), 256, 0, stream>>>(x, mplA, wuplB, 6, u,
            offs, rows, nullptr, nullptr, 4096, 768, 1024, 0);

        k_silumul<<<3072, 256, 0, stream>>>(g, u, z);

        // -- down proj: wd planes (0-5 -> mplA; 6-7 -> over g, dead after silumul)
        k_wsplit<<<dim3(32, 24, 6), 256, 0, stream>>>(wd_l,             mplA,  1024, 768, DxM, EPL_DM);
        k_wsplit<<<dim3(32, 24, 2), 256, 0, stream>>>(wd_l + 6 * DxM,   wdplB, 1024, 768, DxM, EPL_DM);
        k_gemm_s6<0, 2><<<dim3(8, 16, 8), 256, 0, stream>>>(z, mplA, wdplB, 6, nullptr,
            offs, rows, rwgt, h, 4096, 1024, 768, 0);
    }

    k_rmsnorm<1><<<2048, 256, 0, stream>>>(h, finw, nullptr, hn);
    k_transcast<<<dim3(1000, 32), 256, 0, stream>>>(outw, owT);
    k_gemm_bf16<<<dim3(16, 250), 256, 0, stream>>>(hn, owT, out);
}

// Round 5
// 2184.825 us; speedup vs baseline: 1.5269x; 1.2467x over previous
//
#include <hip/hip_runtime.h>
#include <hip/hip_bf16.h>

// Qwen3-MoE forward, MI355X. Router-critical math is fp32-faithful: dense GEMMs
// AND attention run on the bf16 MFMA pipe via an EXACT 3-plane bf16 split
// (x == xh+xm+xl, truncation split, 6 cross products -> rel err ~1e-7).
// R5: back to the verified R2 structure (in-GEMM weight split — weights are
// read exactly once; R4's pre-split pass cost a full extra weight round-trip).
// New vs R2: (a) wg+wu fused into ONE 16-z dispatch (tail-packing: 2x768
// blocks @512 slots -> 1x1536, saves the half-idle rounds); (b) SiLU folded
// into wd's A-load (k_silumul kernel + z-buffer round-trip removed).

constexpr int S_ = 2048, D_ = 1024, H_ = 16, HD_ = 64, E_ = 8, MF_ = 768, V_ = 32000;

typedef short  short8 __attribute__((ext_vector_type(8)));
typedef float  f32x4  __attribute__((ext_vector_type(4)));

static __device__ __forceinline__ unsigned short f2bf(float f) {
    unsigned u = __float_as_uint(f);
    u += 0x7FFF + ((u >> 16) & 1);          // RNE
    return (unsigned short)(u >> 16);
}

static __device__ __forceinline__ short8 u2s8(uint4 u) {
    union { uint4 a; short8 b; } x; x.a = u; return x.b;
}

// ---------------- embed gather ----------------
__global__ __launch_bounds__(256) void k_gather(const int* __restrict__ ids,
                                                const float* __restrict__ emb,
                                                float* __restrict__ h) {
    int tok = blockIdx.x;
    int id  = ids[tok];
    const float4* src = (const float4*)(emb + (long)id * D_);
    float4*       dst = (float4*)(h + (long)tok * D_);
    dst[threadIdx.x] = src[threadIdx.x];
}

// ---------------- rmsnorm (row per block) ----------------
template <int BF>
__global__ __launch_bounds__(256) void k_rmsnorm(const float* __restrict__ in,
                                                 const float* __restrict__ w,
                                                 float* __restrict__ outf,
                                                 unsigned short* __restrict__ outb) {
    int row = blockIdx.x, t = threadIdx.x;
    float4 x = ((const float4*)(in + (long)row * D_))[t];
    float ss = x.x * x.x + x.y * x.y + x.z * x.z + x.w * x.w;
#pragma unroll
    for (int m = 32; m >= 1; m >>= 1) ss += __shfl_xor(ss, m);
    __shared__ float ps[4];
    if ((t & 63) == 0) ps[t >> 6] = ss;
    __syncthreads();
    float tot   = ps[0] + ps[1] + ps[2] + ps[3];
    float scale = 1.0f / sqrtf(tot * (1.0f / D_) + 1e-6f);
    float4 wv = ((const float4*)w)[t];
    float4 o;
    o.x = x.x * scale * wv.x; o.y = x.y * scale * wv.y;
    o.z = x.z * scale * wv.z; o.w = x.w * scale * wv.w;
    if (BF) {
        ushort4 ub;
        ub.x = f2bf(o.x); ub.y = f2bf(o.y); ub.z = f2bf(o.z); ub.w = f2bf(o.w);
        *(ushort4*)(outb + (long)row * D_ + t * 4) = ub;
    } else {
        ((float4*)(outf + (long)row * D_))[t] = o;
    }
}

// ---------------- per-head RMSNorm + RoPE (one wave per (tensor,tok,head)) ----
__global__ __launch_bounds__(256) void k_qkrope(float* __restrict__ q, float* __restrict__ k,
                                                const float* __restrict__ qn,
                                                const float* __restrict__ kn,
                                                const float* __restrict__ cosb,
                                                const float* __restrict__ sinb) {
    int wid  = (blockIdx.x << 2) | (threadIdx.x >> 6);   // 0 .. 65535
    int lane = threadIdx.x & 63;
    int tensor = wid >> 15;
    int rem    = wid & 32767;
    int tok = rem >> 4, head = rem & 15;
    float* ptr = tensor ? k : q;
    const float* nw = tensor ? kn : qn;
    long off = ((long)tok * H_ + head) * HD_ + lane;
    float v = ptr[off];
    float ss = v * v;
#pragma unroll
    for (int m = 32; m >= 1; m >>= 1) ss += __shfl_xor(ss, m);
    float xn = v * (1.0f / sqrtf(ss * (1.0f / HD_) + 1e-6f)) * nw[lane];
    float other = __shfl_xor(xn, 32);
    float rot = (lane < 32) ? -other : other;
    ptr[off] = xn * cosb[tok * HD_ + lane] + rot * sinb[tok * HD_ + lane];
}

// ---------------- exact 3-plane bf16 split helpers ----------------
static __device__ __forceinline__ void splitpack2(float x0, float x1,
                                                  unsigned& wh, unsigned& wm,
                                                  unsigned& wl) {
    unsigned u0 = __float_as_uint(x0), u1 = __float_as_uint(x1);
    unsigned h0 = u0 & 0xFFFF0000u,    h1 = u1 & 0xFFFF0000u;
    float r0 = x0 - __uint_as_float(h0), r1 = x1 - __uint_as_float(h1);
    unsigned m0 = __float_as_uint(r0) & 0xFFFF0000u;
    unsigned m1 = __float_as_uint(r1) & 0xFFFF0000u;
    float s0 = r0 - __uint_as_float(m0), s1 = r1 - __uint_as_float(m1);
    unsigned l0 = __float_as_uint(s0),   l1 = __float_as_uint(s1);
    wh = (h0 >> 16) | h1;
    wm = (m0 >> 16) | m1;
    wl = (l0 >> 16) | (l1 & 0xFFFF0000u);
}

static __device__ __forceinline__ void split8(const float* v,
                                              uint4& qh, uint4& qm, uint4& ql) {
    unsigned ph[4], pm[4], pl[4];
#pragma unroll
    for (int j = 0; j < 4; j++) splitpack2(v[2 * j], v[2 * j + 1], ph[j], pm[j], pl[j]);
    qh = make_uint4(ph[0], ph[1], ph[2], ph[3]);
    qm = make_uint4(pm[0], pm[1], pm[2], pm[3]);
    ql = make_uint4(pl[0], pl[1], pl[2], pl[3]);
}

// ---------------- split-bf16 MFMA GEMM: C[M,N] = A[M,K] @ B[K,N] ----------------
// MODE 0: single B (+ z*bStrideZ experts).  MODE 1: QKV triple (B0/B1/B2 by z,
//   C += z*cStrideZ).  MODE 2: dual wg/wu (z<8 -> B0,C ; z>=8 -> B1,C2; e=z&7).
// ASILU: A-operand = silu(A[p])*A2[p] computed on the fly (wd path; z buffer gone).
// IND: A rows via rows[].  EPI: 0 store, 1 residual add, 2 scaled atomic scatter.
template <int IND, int EPI, int MODE, int ASILU>
__global__ __launch_bounds__(256) void k_gemm_s6(const float* __restrict__ A,
                                                 const float* __restrict__ A2,
                                                 const float* __restrict__ B0,
                                                 const float* __restrict__ B1,
                                                 const float* __restrict__ B2,
                                                 float* __restrict__ C,
                                                 float* __restrict__ C2,
                                                 const int* __restrict__ offs,
                                                 const int* __restrict__ rows,
                                                 const float* __restrict__ rwgt,
                                                 float* __restrict__ hout,
                                                 int Mtot, int N, int K,
                                                 long bStrideZ, long cStrideZ) {
    int z = blockIdx.z;
    int e = (MODE == 2) ? (z & 7) : z;
    int ms, me;
    if (offs) { ms = offs[e]; me = offs[e + 1]; }
    else      { ms = 0; me = Mtot; }
    int p0 = ms + blockIdx.y * 128;
    if (p0 >= me) return;
    const float* Bz;
    if (MODE == 1)      Bz = (z == 0) ? B0 : (z == 1) ? B1 : B2;
    else if (MODE == 2) Bz = ((z < 8) ? B0 : B1) + (long)e * bStrideZ;
    else                Bz = B0 + (long)z * bStrideZ;
    float* Cz;
    if (MODE == 1)      Cz = C + (long)z * cStrideZ;
    else if (MODE == 2) Cz = (z < 8) ? C : C2;
    else                Cz = C;
    int n0 = blockIdx.x * 128;

    __shared__ __align__(16) unsigned short As[3][128][40];  // planes h/m/l, [m][k]
    __shared__ __align__(16) unsigned short Bs[3][128][40];  // planes h/m/l, [n][k]

    int t = threadIdx.x;
    int lane = t & 63, wave = t >> 6;
    int wm = (wave >> 1) * 64, wn = (wave & 1) * 64;
    int ln = lane & 15, lq = lane >> 4;

    f32x4 acc[4][4];
    f32x4 zero4 = {0.f, 0.f, 0.f, 0.f};
#pragma unroll
    for (int r = 0; r < 4; r++)
#pragma unroll
        for (int c = 0; c < 4; c++) acc[r][c] = zero4;

    int arow = t >> 1, ak0 = (t & 1) * 16;   // A: row, k-half of 32
    const float* aptr = nullptr;
    const float* aptr2 = nullptr;
    {
        int pA = p0 + arow;
        if (pA < me) {
            int srow = IND ? rows[pA] : pA;
            aptr = A + (long)srow * K + ak0;
            if (ASILU) aptr2 = A2 + (long)srow * K + ak0;
        }
    }
    int brow = t >> 1, bk0 = (t & 1) * 16;
    const float* bbase = Bz + (n0 + brow);

    for (int k0 = 0; k0 < K; k0 += 32) {
        float va[16];
        if (aptr) {
            if (ASILU) {
#pragma unroll
                for (int c4 = 0; c4 < 4; c4++) {
                    float4 fg = *(const float4*)(aptr  + k0 + c4 * 4);
                    float4 fu = *(const float4*)(aptr2 + k0 + c4 * 4);
                    va[c4 * 4 + 0] = fg.x / (1.f + expf(-fg.x)) * fu.x;
                    va[c4 * 4 + 1] = fg.y / (1.f + expf(-fg.y)) * fu.y;
                    va[c4 * 4 + 2] = fg.z / (1.f + expf(-fg.z)) * fu.z;
                    va[c4 * 4 + 3] = fg.w / (1.f + expf(-fg.w)) * fu.w;
                }
            } else {
#pragma unroll
                for (int c4 = 0; c4 < 4; c4++) {
                    float4 f = *(const float4*)(aptr + k0 + c4 * 4);
                    va[c4 * 4 + 0] = f.x; va[c4 * 4 + 1] = f.y;
                    va[c4 * 4 + 2] = f.z; va[c4 * 4 + 3] = f.w;
                }
            }
        } else {
#pragma unroll
            for (int j = 0; j < 16; j++) va[j] = 0.f;
        }
        uint4 ah0, am0, al0, ah1, am1, al1;
        split8(va,     ah0, am0, al0);
        split8(va + 8, ah1, am1, al1);
        float vb[16];
        {
            const float* bp = bbase + (long)(k0 + bk0) * N;
#pragma unroll
            for (int j = 0; j < 16; j++) vb[j] = bp[(long)j * N];
        }
        uint4 bh0, bm0, bl0, bh1, bm1, bl1;
        split8(vb,     bh0, bm0, bl0);
        split8(vb + 8, bh1, bm1, bl1);

        __syncthreads();
        *(uint4*)&As[0][arow][ak0]     = ah0;
        *(uint4*)&As[0][arow][ak0 + 8] = ah1;
        *(uint4*)&As[1][arow][ak0]     = am0;
        *(uint4*)&As[1][arow][ak0 + 8] = am1;
        *(uint4*)&As[2][arow][ak0]     = al0;
        *(uint4*)&As[2][arow][ak0 + 8] = al1;
        *(uint4*)&Bs[0][brow][bk0]     = bh0;
        *(uint4*)&Bs[0][brow][bk0 + 8] = bh1;
        *(uint4*)&Bs[1][brow][bk0]     = bm0;
        *(uint4*)&Bs[1][brow][bk0 + 8] = bm1;
        *(uint4*)&Bs[2][brow][bk0]     = bl0;
        *(uint4*)&Bs[2][brow][bk0 + 8] = bl1;
        __syncthreads();

        short8 fah[4], fam[4], fal[4];
#pragma unroll
        for (int r = 0; r < 4; r++) {
            fah[r] = *(const short8*)&As[0][wm + 16 * r + ln][lq * 8];
            fam[r] = *(const short8*)&As[1][wm + 16 * r + ln][lq * 8];
            fal[r] = *(const short8*)&As[2][wm + 16 * r + ln][lq * 8];
        }
#pragma unroll
        for (int c = 0; c < 4; c++) {
            short8 fbh = *(const short8*)&Bs[0][wn + 16 * c + ln][lq * 8];
            short8 fbm = *(const short8*)&Bs[1][wn + 16 * c + ln][lq * 8];
            short8 fbl = *(const short8*)&Bs[2][wn + 16 * c + ln][lq * 8];
#pragma unroll
            for (int r = 0; r < 4; r++) {
                f32x4 a2 = acc[r][c];
                a2 = __builtin_amdgcn_mfma_f32_16x16x32_bf16(fah[r], fbh, a2, 0, 0, 0);
                a2 = __builtin_amdgcn_mfma_f32_16x16x32_bf16(fah[r], fbm, a2, 0, 0, 0);
                a2 = __builtin_amdgcn_mfma_f32_16x16x32_bf16(fam[r], fbh, a2, 0, 0, 0);
                a2 = __builtin_amdgcn_mfma_f32_16x16x32_bf16(fah[r], fbl, a2, 0, 0, 0);
                a2 = __builtin_amdgcn_mfma_f32_16x16x32_bf16(fam[r], fbm, a2, 0, 0, 0);
                a2 = __builtin_amdgcn_mfma_f32_16x16x32_bf16(fal[r], fbh, a2, 0, 0, 0);
                acc[r][c] = a2;
            }
        }
    }

    // C/D: col=lane&15, row=(lane>>4)*4+i  [m89-verified]
#pragma unroll
    for (int r = 0; r < 4; r++)
#pragma unroll
        for (int c = 0; c < 4; c++) {
            int rowb = wm + 16 * r + lq * 4;
            int col  = n0 + wn + 16 * c + ln;
#pragma unroll
            for (int i = 0; i < 4; i++) {
                int p = p0 + rowb + i;
                if (p >= me) continue;
                if (EPI == 2) {
                    atomicAdd(hout + (long)rows[p] * N + col, rwgt[p] * acc[r][c][i]);
                } else if (EPI == 1) {
                    float* cp = Cz + (long)p * N + col;
                    *cp += acc[r][c][i];
                } else {
                    Cz[(long)p * N + col] = acc[r][c][i];
                }
            }
        }
}

// ---------------- split-bf16 MFMA flash attention (R2, unchanged) ----------------
__global__ __launch_bounds__(256) void k_attn_mfma(const float* __restrict__ q,
                                                   const float* __restrict__ k,
                                                   const float* __restrict__ v,
                                                   float* __restrict__ o) {
    int head = blockIdx.y;
    int qi = ((blockIdx.y >> 3) & 1) ? (int)(gridDim.x - 1 - blockIdx.x) : (int)blockIdx.x;
    int q0 = qi * 64;

    __shared__ __align__(16) unsigned short Ks[3][64][72];  // [plane][kv][d]
    __shared__ __align__(16) unsigned short Vt[3][64][72];  // [plane][d][kv]
    __shared__ __align__(16) float Ps[64][68];              // [q][kv] fp32

    int t = threadIdx.x;
    int lane = t & 63, w = t >> 6;
    int ln = lane & 15, lq = lane >> 4;

    short8 qh[2], qm[2], qlr[2];
    {
        const float* qp = q + ((long)(q0 + 16 * w + ln) * H_ + head) * HD_;
#pragma unroll
        for (int ks = 0; ks < 2; ks++) {
            float vq[8];
            float4 f0 = *(const float4*)(qp + 32 * ks + lq * 8);
            float4 f1 = *(const float4*)(qp + 32 * ks + lq * 8 + 4);
            vq[0] = f0.x; vq[1] = f0.y; vq[2] = f0.z; vq[3] = f0.w;
            vq[4] = f1.x; vq[5] = f1.y; vq[6] = f1.z; vq[7] = f1.w;
            uint4 hh, mm, ll;
            split8(vq, hh, mm, ll);
            qh[ks] = u2s8(hh); qm[ks] = u2s8(mm); qlr[ks] = u2s8(ll);
        }
    }

    f32x4 oc[4];
    f32x4 zero4 = {0.f, 0.f, 0.f, 0.f};
#pragma unroll
    for (int c = 0; c < 4; c++) oc[c] = zero4;
    float m_run[4], l_run[4];
#pragma unroll
    for (int i = 0; i < 4; i++) { m_run[i] = -3.402823466e38f; l_run[i] = 0.f; }

    for (int kt = 0; kt <= qi; kt++) {
        __syncthreads();
        {
            int kr = t >> 2, kq4 = (t & 3) * 16;
            const float* kp = k + ((long)(kt * 64 + kr) * H_ + head) * HD_ + kq4;
            float vk[16];
#pragma unroll
            for (int j = 0; j < 4; j++) {
                float4 f = *(const float4*)(kp + 4 * j);
                vk[4 * j + 0] = f.x; vk[4 * j + 1] = f.y;
                vk[4 * j + 2] = f.z; vk[4 * j + 3] = f.w;
            }
            uint4 h0, m0, l0, h1, m1, l1;
            split8(vk,     h0, m0, l0);
            split8(vk + 8, h1, m1, l1);
            *(uint4*)&Ks[0][kr][kq4]     = h0; *(uint4*)&Ks[0][kr][kq4 + 8] = h1;
            *(uint4*)&Ks[1][kr][kq4]     = m0; *(uint4*)&Ks[1][kr][kq4 + 8] = m1;
            *(uint4*)&Ks[2][kr][kq4]     = l0; *(uint4*)&Ks[2][kr][kq4 + 8] = l1;
            const float* vp = v + ((long)(kt * 64 + lane) * H_ + head) * HD_ + w * 16;
            float vvv[16];
#pragma unroll
            for (int j = 0; j < 4; j++) {
                float4 f = *(const float4*)(vp + 4 * j);
                vvv[4 * j + 0] = f.x; vvv[4 * j + 1] = f.y;
                vvv[4 * j + 2] = f.z; vvv[4 * j + 3] = f.w;
            }
#pragma unroll
            for (int j = 0; j < 16; j++) {
                float x = vvv[j];
                unsigned uu = __float_as_uint(x);
                unsigned hh = uu & 0xFFFF0000u;
                float rr = x - __uint_as_float(hh);
                unsigned mm2 = __float_as_uint(rr) & 0xFFFF0000u;
                float ss2 = rr - __uint_as_float(mm2);
                Vt[0][w * 16 + j][lane] = (unsigned short)(hh >> 16);
                Vt[1][w * 16 + j][lane] = (unsigned short)(mm2 >> 16);
                Vt[2][w * 16 + j][lane] = (unsigned short)(__float_as_uint(ss2) >> 16);
            }
        }
        __syncthreads();

        f32x4 sc[4];
#pragma unroll
        for (int c = 0; c < 4; c++) sc[c] = zero4;
#pragma unroll
        for (int ks = 0; ks < 2; ks++) {
#pragma unroll
            for (int c = 0; c < 4; c++) {
                const int co = 16 * c + ln, ko = 32 * ks + lq * 8;
                short8 bh = *(const short8*)&Ks[0][co][ko];
                short8 bm = *(const short8*)&Ks[1][co][ko];
                short8 bl = *(const short8*)&Ks[2][co][ko];
                f32x4 a2 = sc[c];
                a2 = __builtin_amdgcn_mfma_f32_16x16x32_bf16(qh[ks],  bh, a2, 0, 0, 0);
                a2 = __builtin_amdgcn_mfma_f32_16x16x32_bf16(qh[ks],  bm, a2, 0, 0, 0);
                a2 = __builtin_amdgcn_mfma_f32_16x16x32_bf16(qm[ks],  bh, a2, 0, 0, 0);
                a2 = __builtin_amdgcn_mfma_f32_16x16x32_bf16(qh[ks],  bl, a2, 0, 0, 0);
                a2 = __builtin_amdgcn_mfma_f32_16x16x32_bf16(qm[ks],  bm, a2, 0, 0, 0);
                a2 = __builtin_amdgcn_mfma_f32_16x16x32_bf16(qlr[ks], bh, a2, 0, 0, 0);
                sc[c] = a2;
            }
        }

#pragma unroll
        for (int i = 0; i < 4; i++) {
            int qg = q0 + 16 * w + 4 * lq + i;
            float mx = -3.402823466e38f;
#pragma unroll
            for (int c = 0; c < 4; c++) {
                int kvg = kt * 64 + 16 * c + ln;
                float s = sc[c][i] * 0.125f;
                s = (kvg <= qg) ? s : -3.402823466e38f;
                sc[c][i] = s;
                mx = fmaxf(mx, s);
            }
            mx = fmaxf(mx, __shfl_xor(mx, 1));
            mx = fmaxf(mx, __shfl_xor(mx, 2));
            mx = fmaxf(mx, __shfl_xor(mx, 4));
            mx = fmaxf(mx, __shfl_xor(mx, 8));
            float mn = fmaxf(m_run[i], mx);
            float al = expf(m_run[i] - mn);
            m_run[i] = mn;
            float sum = 0.f;
#pragma unroll
            for (int c = 0; c < 4; c++) {
                float e = expf(sc[c][i] - mn);
                Ps[16 * w + 4 * lq + i][16 * c + ln] = e;
                sum += e;
            }
            sum += __shfl_xor(sum, 1);
            sum += __shfl_xor(sum, 2);
            sum += __shfl_xor(sum, 4);
            sum += __shfl_xor(sum, 8);
            l_run[i] = l_run[i] * al + sum;
#pragma unroll
            for (int c = 0; c < 4; c++) oc[c][i] *= al;
        }

#pragma unroll
        for (int ks = 0; ks < 2; ks++) {
            float pv8[8];
            *(float4*)&pv8[0] = *(const float4*)&Ps[16 * w + ln][32 * ks + lq * 8];
            *(float4*)&pv8[4] = *(const float4*)&Ps[16 * w + ln][32 * ks + lq * 8 + 4];
            uint4 ph4, pm4, pl4;
            split8(pv8, ph4, pm4, pl4);
            short8 pah = u2s8(ph4), pam = u2s8(pm4), pal = u2s8(pl4);
#pragma unroll
            for (int c = 0; c < 4; c++) {
                const int co = 16 * c + ln, ko = 32 * ks + lq * 8;
                short8 bh = *(const short8*)&Vt[0][co][ko];
                short8 bm = *(const short8*)&Vt[1][co][ko];
                short8 bl = *(const short8*)&Vt[2][co][ko];
                f32x4 a2 = oc[c];
                a2 = __builtin_amdgcn_mfma_f32_16x16x32_bf16(pah, bh, a2, 0, 0, 0);
                a2 = __builtin_amdgcn_mfma_f32_16x16x32_bf16(pah, bm, a2, 0, 0, 0);
                a2 = __builtin_amdgcn_mfma_f32_16x16x32_bf16(pam, bh, a2, 0, 0, 0);
                a2 = __builtin_amdgcn_mfma_f32_16x16x32_bf16(pah, bl, a2, 0, 0, 0);
                a2 = __builtin_amdgcn_mfma_f32_16x16x32_bf16(pam, bm, a2, 0, 0, 0);
                a2 = __builtin_amdgcn_mfma_f32_16x16x32_bf16(pal, bh, a2, 0, 0, 0);
                oc[c] = a2;
            }
        }
    }

#pragma unroll
    for (int i = 0; i < 4; i++) {
        float invl = 1.0f / l_run[i];
        int qg = q0 + 16 * w + 4 * lq + i;
        float* op = o + ((long)qg * H_ + head) * HD_;
#pragma unroll
        for (int c = 0; c < 4; c++) op[16 * c + ln] = oc[c][i] * invl;
    }
}

// ---------------- router: gate logits, softmax-top2 (stable), counts --------
__global__ __launch_bounds__(256) void k_router(const float* __restrict__ x,
                                                const float* __restrict__ gw,
                                                int* __restrict__ idx, float* __restrict__ wgt,
                                                int* __restrict__ cnt) {
    int tok  = (blockIdx.x << 2) | (threadIdx.x >> 6);
    int lane = threadIdx.x & 63;
    float acc[8] = {0.f, 0.f, 0.f, 0.f, 0.f, 0.f, 0.f, 0.f};
    for (int i = 0; i < 16; i++) {
        int d = lane + i * 64;
        float xv = x[(long)tok * D_ + d];
        const float* gp = gw + (long)d * E_;
#pragma unroll
        for (int e = 0; e < 8; e++) acc[e] = fmaf(xv, gp[e], acc[e]);
    }
#pragma unroll
    for (int e = 0; e < 8; e++)
#pragma unroll
        for (int m = 32; m >= 1; m >>= 1) acc[e] += __shfl_xor(acc[e], m);
    if (lane == 0) {
        int i1 = 0; float m1 = acc[0];
        for (int e = 1; e < 8; e++) if (acc[e] > m1) { m1 = acc[e]; i1 = e; }
        int i2 = -1; float m2 = -3.402823466e38f;
        for (int e = 0; e < 8; e++) if (e != i1 && acc[e] > m2) { m2 = acc[e]; i2 = e; }
        float w1 = 1.0f / (1.0f + expf(m2 - m1));
        idx[tok * 2] = i1; idx[tok * 2 + 1] = i2;
        wgt[tok * 2] = w1; wgt[tok * 2 + 1] = 1.0f - w1;
        atomicAdd(&cnt[i1], 1);
        atomicAdd(&cnt[i2], 1);
    }
}

__global__ void k_offsets(const int* __restrict__ cnt, int* __restrict__ off) {
    if (threadIdx.x == 0) {
        int run = 0;
        for (int e = 0; e < 8; e++) { off[e] = run; run += cnt[e]; }
        off[8] = run;
    }
}

__global__ __launch_bounds__(256) void k_scatter(const int* __restrict__ idx,
                                                 const float* __restrict__ wgt,
                                                 const int* __restrict__ off,
                                                 int* __restrict__ fill,
                                                 int* __restrict__ rows,
                                                 float* __restrict__ rwgt) {
    int tok = blockIdx.x * 256 + threadIdx.x;
#pragma unroll
    for (int j = 0; j < 2; j++) {
        int e = idx[tok * 2 + j];
        int pos = off[e] + atomicAdd(&fill[e], 1);
        rows[pos] = tok;
        rwgt[pos] = wgt[tok * 2 + j];
    }
}

// ---------------- transpose + cast: out_w (1024,32000) f32 -> (32000,1024) bf16
__global__ __launch_bounds__(256) void k_transcast(const float* __restrict__ in,
                                                   unsigned short* __restrict__ out) {
    int c0 = blockIdx.x * 32;   // n
    int r0 = blockIdx.y * 32;   // k
    __shared__ __align__(16) float T[32][36];
    int t = threadIdx.x;
    {
        int row = t >> 3, cq = (t & 7) * 4;
        *(float4*)&T[row][cq] = *(const float4*)(in + (long)(r0 + row) * V_ + c0 + cq);
    }
    __syncthreads();
    {
        int n = t >> 3, kq = (t & 7) * 4;
        ushort4 u;
        u.x = f2bf(T[kq + 0][n]); u.y = f2bf(T[kq + 1][n]);
        u.z = f2bf(T[kq + 2][n]); u.w = f2bf(T[kq + 3][n]);
        *(ushort4*)(out + (long)(c0 + n) * D_ + r0 + kq) = u;
    }
}

// ---------------- bf16 MFMA GEMM for logits (R2 LDS version) ----------------
__global__ __launch_bounds__(256) void k_gemm_bf16(const unsigned short* __restrict__ A,
                                                   const unsigned short* __restrict__ BT,
                                                   float* __restrict__ C) {
    int m0 = blockIdx.x * 128, n0 = blockIdx.y * 128;
    __shared__ __align__(16) unsigned short As[128][40];
    __shared__ __align__(16) unsigned short Bs[128][40];
    int t = threadIdx.x;
    int lane = t & 63, wave = t >> 6;
    int wm = (wave >> 1) * 64, wn = (wave & 1) * 64;
    int ln = lane & 15, lq = lane >> 4;
    f32x4 acc[4][4];
    f32x4 zero4 = {0.f, 0.f, 0.f, 0.f};
#pragma unroll
    for (int r = 0; r < 4; r++)
#pragma unroll
        for (int c = 0; c < 4; c++) acc[r][c] = zero4;
    int rowA = t >> 1;
    int q1 = (t * 2) & 3, q2 = (t * 2 + 1) & 3;
    for (int k0 = 0; k0 < 1024; k0 += 32) {
        const uint4* ap = (const uint4*)(A + (long)(m0 + rowA) * 1024 + k0);
        const uint4* bp = (const uint4*)(BT + (long)(n0 + rowA) * 1024 + k0);
        uint4 a0 = ap[q1], a1 = ap[q2];
        uint4 b0 = bp[q1], b1 = bp[q2];
        __syncthreads();
        *(uint4*)&As[rowA][q1 * 8] = a0;
        *(uint4*)&As[rowA][q2 * 8] = a1;
        *(uint4*)&Bs[rowA][q1 * 8] = b0;
        *(uint4*)&Bs[rowA][q2 * 8] = b1;
        __syncthreads();
        short8 a[4], b[4];
#pragma unroll
        for (int r = 0; r < 4; r++) a[r] = *(const short8*)&As[wm + 16 * r + ln][lq * 8];
#pragma unroll
        for (int c = 0; c < 4; c++) b[c] = *(const short8*)&Bs[wn + 16 * c + ln][lq * 8];
#pragma unroll
        for (int r = 0; r < 4; r++)
#pragma unroll
            for (int c = 0; c < 4; c++)
                acc[r][c] = __builtin_amdgcn_mfma_f32_16x16x32_bf16(a[r], b[c], acc[r][c], 0, 0, 0);
    }
#pragma unroll
    for (int r = 0; r < 4; r++)
#pragma unroll
        for (int c = 0; c < 4; c++) {
            int row = m0 + wm + 16 * r + lq * 4;
            int col = n0 + wn + 16 * c + ln;
#pragma unroll
            for (int i = 0; i < 4; i++)
                C[(long)(row + i) * V_ + col] = acc[r][c][i];
        }
}

// ---------------- host ----------------
extern "C" void kernel_launch(void* const* d_in, const int* in_sizes, int n_in,
                              void* d_out, int out_size, void* d_ws, size_t ws_size,
                              hipStream_t stream) {
    (void)in_sizes; (void)n_in; (void)out_size; (void)ws_size;
    const int*   ids   = (const int*)d_in[0];
    const float* embed = (const float*)d_in[1];
    const float* wq    = (const float*)d_in[2];
    const float* wk    = (const float*)d_in[3];
    const float* wv    = (const float*)d_in[4];
    const float* wo    = (const float*)d_in[5];
    const float* qnw   = (const float*)d_in[6];
    const float* knw   = (const float*)d_in[7];
    const float* anw   = (const float*)d_in[8];
    const float* fnw   = (const float*)d_in[9];
    const float* gatew = (const float*)d_in[10];
    const float* wgate = (const float*)d_in[11];
    const float* wup   = (const float*)d_in[12];
    const float* wdown = (const float*)d_in[13];
    const float* finw  = (const float*)d_in[14];
    const float* outw  = (const float*)d_in[15];
    const float* cosb  = (const float*)d_in[16];
    const float* sinb  = (const float*)d_in[17];
    float* out = (float*)d_out;

    char* w = (char*)d_ws;
    float* h  = (float*)(w);
    float* x  = (float*)(w + 8388608);
    float* q  = (float*)(w + 16777216);
    float* kk = (float*)(w + 25165824);
    float* vv = (float*)(w + 33554432);
    float* ao = (float*)(w + 41943040);
    float* g  = (float*)(w + 50331648);
    float* u  = (float*)(w + 62914560);
    unsigned short* hn  = (unsigned short*)(w + 88080384);
    unsigned short* owT = (unsigned short*)(w + 16777216);  // overlays q..u (dead by then)
    char* rbase = w + 92274688;
    int*   idx  = (int*)(rbase);
    float* wgt  = (float*)(rbase + 16384);
    int*   cnt  = (int*)(rbase + 32768);
    int*   fill = (int*)(rbase + 32768 + 32);
    int*   offs = (int*)(rbase + 32768 + 64);
    int*   rows = (int*)(rbase + 32768 + 128);
    float* rwgt = (float*)(rbase + 32768 + 128 + 16384);

    k_gather<<<2048, 256, 0, stream>>>(ids, embed, h);

    for (int l = 0; l < 2; l++) {
        const float* wq_l = wq + (long)l * D_ * D_;
        const float* wk_l = wk + (long)l * D_ * D_;
        const float* wv_l = wv + (long)l * D_ * D_;
        const float* wo_l = wo + (long)l * D_ * D_;
        const float* an_l = anw + l * D_;
        const float* fn_l = fnw + l * D_;
        const float* qn_l = qnw + l * HD_;
        const float* kn_l = knw + l * HD_;
        const float* gw_l = gatew + (long)l * D_ * E_;
        const float* wg_l = wgate + (long)l * E_ * D_ * MF_;
        const float* wu_l = wup   + (long)l * E_ * D_ * MF_;
        const float* wd_l = wdown + (long)l * E_ * MF_ * D_;

        k_rmsnorm<0><<<2048, 256, 0, stream>>>(h, an_l, x, nullptr);
        // fused QKV: z in {0,1,2} selects wq/wk/wv; C = q + z*2M floats
        k_gemm_s6<0, 0, 1, 0><<<dim3(8, 16, 3), 256, 0, stream>>>(
            x, nullptr, wq_l, wk_l, wv_l, q, nullptr,
            nullptr, nullptr, nullptr, nullptr, 2048, 1024, 1024, 0, 2048L * 1024);
        k_qkrope<<<16384, 256, 0, stream>>>(q, kk, qn_l, kn_l, cosb, sinb);
        k_attn_mfma<<<dim3(32, 16), 256, 0, stream>>>(q, kk, vv, ao);
        k_gemm_s6<0, 1, 0, 0><<<dim3(8, 16, 1), 256, 0, stream>>>(
            ao, nullptr, wo_l, nullptr, nullptr, h, nullptr,
            nullptr, nullptr, nullptr, nullptr, 2048, 1024, 1024, 0, 0);
        k_rmsnorm<0><<<2048, 256, 0, stream>>>(h, fn_l, x, nullptr);
        hipMemsetAsync(cnt, 0, 64, stream);
        k_router<<<512, 256, 0, stream>>>(x, gw_l, idx, wgt, cnt);
        k_offsets<<<1, 64, 0, stream>>>(cnt, offs);
        k_scatter<<<8, 256, 0, stream>>>(idx, wgt, offs, fill, rows, rwgt);
        // fused wg+wu: z 0..7 -> gate (C=g), z 8..15 -> up (C2=u); e = z&7
        k_gemm_s6<1, 0, 2, 0><<<dim3(6, 16, 16), 256, 0, stream>>>(
            x, nullptr, wg_l, wu_l, nullptr, g, u,
            offs, rows, nullptr, nullptr, 4096, 768, 1024, (long)D_ * MF_, 0);
        // wd with fused SiLU: A = silu(g)*u on the fly, scaled atomic scatter into h
        k_gemm_s6<0, 2, 0, 1><<<dim3(8, 16, 8), 256, 0, stream>>>(
            g, u, wd_l, nullptr, nullptr, nullptr, nullptr,
            offs, rows, rwgt, h, 4096, 1024, 768, (long)MF_ * D_, 0);
    }

    k_rmsnorm<1><<<2048, 256, 0, stream>>>(h, finw, nullptr, hn);
    k_transcast<<<dim3(1000, 32), 256, 0, stream>>>(outw, owT);
    k_gemm_bf16<<<dim3(16, 250), 256, 0, stream>>>(hn, owT, out);
}